// Round 4
// baseline (30140.088 us; speedup 1.0000x reference)
//
#include <hip/hip_runtime.h>
#include <stdint.h>

typedef unsigned short u16;
typedef short bf16x8 __attribute__((ext_vector_type(8)));
typedef float f32x4 __attribute__((ext_vector_type(4)));

__device__ __forceinline__ float bf2f(u16 u) {
  union { uint32_t i; float f; } v; v.i = ((uint32_t)u) << 16; return v.f;
}
__device__ __forceinline__ u16 f2bf(float f) {
  union { float f; uint32_t i; } v; v.f = f;
  uint32_t x = v.i;
  return (u16)((x + 0x7FFFu + ((x >> 16) & 1u)) >> 16);
}
__device__ __forceinline__ float sigm(float x) { return 1.f / (1.f + expf(-x)); }

// ---------------- packing ----------------
// Wih/Whh [2000][500] f32 -> [2048][512] bf16, rows interleaved c = j*4+g
__global__ void packgate_k(const float* __restrict__ src, u16* __restrict__ dst) {
  int idx = blockIdx.x * 256 + threadIdx.x;
  if (idx >= 2048 * 512) return;
  int crow = idx >> 9, k = idx & 511;
  int j = crow >> 2, g = crow & 3;
  u16 v = 0;
  if (j < 500 && k < 500) v = f2bf(src[(size_t)(g * 500 + j) * 500 + k]);
  dst[idx] = v;
}

__global__ void gatebias_k(const float* __restrict__ bih, const float* __restrict__ bhh,
                           float* __restrict__ dst) {
  int c = blockIdx.x * 256 + threadIdx.x;
  if (c >= 2048) return;
  int j = c >> 2, g = c & 3;
  dst[c] = (j < 500) ? bih[g * 500 + j] + bhh[g * 500 + j] : 0.f;
}

// src f32 [Ks][Ns] -> dst bf16 [Nd][Kd] (transposed, zero-padded)
__global__ void packT_k(const float* __restrict__ src, int Ks, int Ns,
                        u16* __restrict__ dst, int Nd, int Kd) {
  int idx = blockIdx.x * 256 + threadIdx.x;
  if (idx >= Nd * Kd) return;
  int n = idx / Kd, k = idx - n * Kd;
  dst[idx] = (n < Ns && k < Ks) ? f2bf(src[(size_t)k * Ns + n]) : (u16)0;
}

__global__ void padbias_k(const float* __restrict__ s, int Ns, float* __restrict__ dst, int Nd) {
  int i = blockIdx.x * 256 + threadIdx.x;
  if (i >= Nd) return;
  dst[i] = (i < Ns) ? s[i] : 0.f;
}

// ---------------- c1 = W2^T W1+, c2 = W2^T W1- ----------------
__global__ void c12_k(const float* __restrict__ W1, const float* __restrict__ W2,
                      float* __restrict__ c1, float* __restrict__ c2) {
  int f = blockIdx.x * 256 + threadIdx.x;
  if (f >= 512) return;
  float s1 = 0.f, s2 = 0.f;
  if (f < 500) {
    for (int g = 0; g < 500; g++) {
      float w = W1[g];
      float v = W2[(size_t)g * 500 + f];
      s1 = fmaf(fmaxf(w, 0.f), v, s1);
      s2 = fmaf(fminf(w, 0.f), v, s2);
    }
  }
  c1[f] = s1; c2[f] = s2;
}

// ---------------- p = A@(A@x)+, q = A@(A@x)- ----------------
__global__ void pq_k(const float* __restrict__ x, const float* __restrict__ A,
                     float* __restrict__ p, float* __restrict__ q) {
  __shared__ float xs[120], axp[120], axm[120];
  int bt = blockIdx.x, tid = threadIdx.x;
  int t = bt >> 2, b = bt & 3;
  if (tid < 120) xs[tid] = x[(size_t)(b * 192 + t) * 120 + tid];
  __syncthreads();
  if (tid < 120) {
    const float* Ar = A + tid * 120;
    float s = 0.f;
    for (int j = 0; j < 120; j++) s = fmaf(Ar[j], xs[j], s);
    axp[tid] = fmaxf(s, 0.f);
    axm[tid] = fminf(s, 0.f);
  }
  __syncthreads();
  if (tid < 120) {
    const float* Ar = A + tid * 120;
    float sp = 0.f, sm = 0.f;
    for (int j = 0; j < 120; j++) { float a = Ar[j]; sp = fmaf(a, axp[j], sp); sm = fmaf(a, axm[j], sm); }
    int o = t * 480 + b * 120 + tid;
    p[o] = sp; q[o] = sm;
  }
}

// ---------------- h2 = relu(p*c1 + q*c2), bf16 rows ----------------
__global__ void h2mat_k(const float* __restrict__ p, const float* __restrict__ q,
                        const float* __restrict__ c1, const float* __restrict__ c2,
                        u16* __restrict__ h2c, int R0) {
  int row = blockIdx.x * 4 + (threadIdx.x >> 6);
  int go = (threadIdx.x & 63) * 8;
  float pv = p[R0 + row], qv = q[R0 + row];
  alignas(16) u16 o[8];
  #pragma unroll
  for (int i = 0; i < 8; i++) {
    float v = pv * c1[go + i] + qv * c2[go + i];
    o[i] = f2bf(fmaxf(v, 0.f));
  }
  *(uint4*)&h2c[(size_t)row * 512 + go] = *(const uint4*)o;
}

// ---------------- LDS-staged gates GEMM: C = A @ B^T + bias (bf16 out) ----------------
// A [M][512] bf16, B [2048][512] bf16. C [M][2048] bf16. Grid (16, M/128), 256 thr.
__global__ __launch_bounds__(256, 2) void gemm_lds_k(
    const u16* __restrict__ A, const u16* __restrict__ B,
    const float* __restrict__ bias, u16* __restrict__ C, int M) {
  __shared__ u16 Al[2][128][32];
  __shared__ u16 Bl[2][128][32];
  const int tid = threadIdx.x, wid = tid >> 6, lane = tid & 63;
  const int lr = lane & 15, g4 = lane >> 4;
  const int m0 = blockIdx.y * 128, n0 = blockIdx.x * 128;
  const int ms = (wid & 1) * 64, ns = (wid >> 1) * 64;
  const int srow = tid >> 1, shalf = (tid & 1) * 16;
  const u16* Asrc = A + (size_t)(m0 + srow) * 512 + shalf;
  const u16* Bsrc = B + (size_t)(n0 + srow) * 512 + shalf;

  f32x4 acc[4][4];
  #pragma unroll
  for (int i = 0; i < 4; i++)
    #pragma unroll
    for (int j = 0; j < 4; j++) acc[i][j] = (f32x4){0.f, 0.f, 0.f, 0.f};

  uint4 ra0, ra1, rb0, rb1;
  // prologue: load tile0, write buf0, load tile1
  ra0 = *(const uint4*)(Asrc + 0);  ra1 = *(const uint4*)(Asrc + 8);
  rb0 = *(const uint4*)(Bsrc + 0);  rb1 = *(const uint4*)(Bsrc + 8);
  *(uint4*)&Al[0][srow][shalf] = ra0; *(uint4*)&Al[0][srow][shalf + 8] = ra1;
  *(uint4*)&Bl[0][srow][shalf] = rb0; *(uint4*)&Bl[0][srow][shalf + 8] = rb1;
  ra0 = *(const uint4*)(Asrc + 32); ra1 = *(const uint4*)(Asrc + 40);
  rb0 = *(const uint4*)(Bsrc + 32); rb1 = *(const uint4*)(Bsrc + 40);
  __syncthreads();

  #pragma unroll
  for (int kt = 0; kt < 16; kt++) {
    const int cur = kt & 1;
    if (kt < 15) {   // write tile kt+1 into the other buffer
      *(uint4*)&Al[cur ^ 1][srow][shalf] = ra0; *(uint4*)&Al[cur ^ 1][srow][shalf + 8] = ra1;
      *(uint4*)&Bl[cur ^ 1][srow][shalf] = rb0; *(uint4*)&Bl[cur ^ 1][srow][shalf + 8] = rb1;
    }
    if (kt < 14) {   // load tile kt+2
      ra0 = *(const uint4*)(Asrc + (kt + 2) * 32);     ra1 = *(const uint4*)(Asrc + (kt + 2) * 32 + 8);
      rb0 = *(const uint4*)(Bsrc + (kt + 2) * 32);     rb1 = *(const uint4*)(Bsrc + (kt + 2) * 32 + 8);
    }
    bf16x8 av[4], bv[4];
    #pragma unroll
    for (int i = 0; i < 4; i++) av[i] = *(const bf16x8*)&Al[cur][ms + i * 16 + lr][g4 * 8];
    #pragma unroll
    for (int j = 0; j < 4; j++) bv[j] = *(const bf16x8*)&Bl[cur][ns + j * 16 + lr][g4 * 8];
    #pragma unroll
    for (int i = 0; i < 4; i++)
      #pragma unroll
      for (int j = 0; j < 4; j++)
        acc[i][j] = __builtin_amdgcn_mfma_f32_16x16x32_bf16(av[i], bv[j], acc[i][j], 0, 0, 0);
    __syncthreads();
  }

  #pragma unroll
  for (int i = 0; i < 4; i++)
    #pragma unroll
    for (int r = 0; r < 4; r++) {
      int m = m0 + ms + i * 16 + g4 * 4 + r;
      #pragma unroll
      for (int j = 0; j < 4; j++) {
        int n = n0 + ns + j * 16 + lr;
        C[(size_t)m * 2048 + n] = f2bf(acc[i][j][r] + bias[n]);
      }
    }
}

// ---------------- persistent LSTM: all steps [t0,t1), 30 independent blocks ----------------
// Whh [2048][512] interleaved; gates rows (t-gbase)*480+m; c/h persistent in cbuf/hbuf.
__global__ __launch_bounds__(256, 1) void lstm_persist_k(
    const u16* __restrict__ Whh, const u16* __restrict__ gates,
    float* __restrict__ cbuf, u16* __restrict__ hbuf,
    int t0, int t1, int gbase) {
  __shared__ u16 hls[16][516];
  __shared__ u16 gls[4][16][260];
  const int tid = threadIdx.x, wid = tid >> 6, lane = tid & 63;
  const int lr = lane & 15, g4 = lane >> 4;
  const int m0 = blockIdx.x * 16;

  float c[32];
  if (t0 == 0) {
    for (int e = tid; e < 16 * 516; e += 256) ((u16*)hls)[e] = 0;
    #pragma unroll
    for (int s = 0; s < 32; s++) c[s] = 0.f;
  } else {
    for (int e = tid; e < 8192; e += 256)
      hls[e >> 9][e & 511] = hbuf[(size_t)(m0 + (e >> 9)) * 512 + (e & 511)];
    #pragma unroll
    for (int s = 0; s < 32; s++)
      c[s] = cbuf[(size_t)(m0 + lr) * 512 + (wid * 32 + s) * 4 + g4];
  }
  __syncthreads();

  for (int t = t0; t < t1; ++t) {
    const u16* gsrc = gates + ((size_t)(t - gbase) * 480 + m0) * 2048;
    // issue half-0 gate loads (own-wave cols [wid*512, wid*512+256))
    uint4 r0[8], r1[8];
    #pragma unroll
    for (int i = 0; i < 8; i++) {
      int e = i * 64 + lane, row = e >> 5, ch = e & 31;
      r0[i] = *(const uint4*)(gsrc + (size_t)row * 2048 + wid * 512 + ch * 8);
    }
    // hoist A fragments (h) for the whole step
    bf16x8 av[16];
    #pragma unroll
    for (int kk = 0; kk < 16; kk++)
      av[kk] = *(const bf16x8*)&hls[lr][kk * 32 + g4 * 8];
    __syncthreads();   // all waves hoisted before any cell overwrites hls

    // ---- half 0: n-tiles s = 0..15 (cols [wid*512, wid*512+256)) ----
    f32x4 acc[16];
    #pragma unroll
    for (int s = 0; s < 16; s++) acc[s] = (f32x4){0.f, 0.f, 0.f, 0.f};
    #pragma unroll
    for (int kk = 0; kk < 16; kk++) {
      #pragma unroll
      for (int s = 0; s < 16; s++) {
        bf16x8 bv = *(const bf16x8*)(Whh + (size_t)(wid * 512 + s * 16 + lr) * 512 + kk * 32 + g4 * 8);
        acc[s] = __builtin_amdgcn_mfma_f32_16x16x32_bf16(bv, av[kk], acc[s], 0, 0, 0);
      }
    }
    // issue half-1 gate loads (latency hides under half-1 MFMAs)
    #pragma unroll
    for (int i = 0; i < 8; i++) {
      int e = i * 64 + lane, row = e >> 5, ch = e & 31;
      r1[i] = *(const uint4*)(gsrc + (size_t)row * 2048 + wid * 512 + 256 + ch * 8);
    }
    // stage half-0 gates to own-wave LDS section, then cells
    #pragma unroll
    for (int i = 0; i < 8; i++) {
      int e = i * 64 + lane, row = e >> 5, ch = e & 31;
      *(uint4*)&gls[wid][row][ch * 8] = r0[i];
    }
    #pragma unroll
    for (int s = 0; s < 16; s++) {
      const u16* q = &gls[wid][lr][s * 16 + g4 * 4];
      float gi = bf2f(q[0]) + acc[s][0];
      float gf = bf2f(q[1]) + acc[s][1];
      float gg = bf2f(q[2]) + acc[s][2];
      float go = bf2f(q[3]) + acc[s][3];
      float cn = sigm(gf) * c[s] + sigm(gi) * tanhf(gg);
      c[s] = cn;
      hls[lr][(wid * 32 + s) * 4 + g4] = f2bf(sigm(go) * tanhf(cn));
    }

    // ---- half 1: n-tiles s = 0..15 (cols [wid*512+256, wid*512+512)) ----
    #pragma unroll
    for (int s = 0; s < 16; s++) acc[s] = (f32x4){0.f, 0.f, 0.f, 0.f};
    #pragma unroll
    for (int kk = 0; kk < 16; kk++) {
      #pragma unroll
      for (int s = 0; s < 16; s++) {
        bf16x8 bv = *(const bf16x8*)(Whh + (size_t)(wid * 512 + 256 + s * 16 + lr) * 512 + kk * 32 + g4 * 8);
        acc[s] = __builtin_amdgcn_mfma_f32_16x16x32_bf16(bv, av[kk], acc[s], 0, 0, 0);
      }
    }
    #pragma unroll
    for (int i = 0; i < 8; i++) {
      int e = i * 64 + lane, row = e >> 5, ch = e & 31;
      *(uint4*)&gls[wid][row][ch * 8] = r1[i];
    }
    #pragma unroll
    for (int s = 0; s < 16; s++) {
      const u16* q = &gls[wid][lr][s * 16 + g4 * 4];
      float gi = bf2f(q[0]) + acc[s][0];
      float gf = bf2f(q[1]) + acc[s][1];
      float gg = bf2f(q[2]) + acc[s][2];
      float go = bf2f(q[3]) + acc[s][3];
      int sg = 16 + s;
      float cn = sigm(gf) * c[sg] + sigm(gi) * tanhf(gg);
      c[sg] = cn;
      hls[lr][(wid * 32 + sg) * 4 + g4] = f2bf(sigm(go) * tanhf(cn));
    }
    __syncthreads();   // hls complete for next step; gls consumed
  }

  // persist state
  for (int e = tid; e < 8192; e += 256)
    hbuf[(size_t)(m0 + (e >> 9)) * 512 + (e & 511)] = hls[e >> 9][e & 511];
  #pragma unroll
  for (int s = 0; s < 32; s++)
    cbuf[(size_t)(m0 + lr) * 512 + (wid * 32 + s) * 4 + g4] = c[s];
}

// ---------------- direct MFMA GEMM (MLP head) ----------------
template<int BM, int BN, int WM, int WN, int ACT, int OUTK>
__global__ __launch_bounds__(256) void mgemm_k(
    const u16* __restrict__ A, int lda,
    const u16* __restrict__ B, int ldb,
    const float* __restrict__ bias,
    void* __restrict__ Cv, int ldc, int M, int K) {
  constexpr int FM = BM / (WM * 16), FN = BN / (WN * 16);
  const int tid = threadIdx.x;
  const int wid = tid >> 6, lane = tid & 63;
  const int lr = lane & 15, lko = (lane >> 4) << 3;
  const int m0 = blockIdx.y * BM + (wid % WM) * (FM * 16);
  const int n0 = blockIdx.x * BN + (wid / WM) * (FN * 16);

  f32x4 acc[FM][FN];
  #pragma unroll
  for (int i = 0; i < FM; i++)
    #pragma unroll
    for (int j = 0; j < FN; j++) acc[i][j] = (f32x4){0.f, 0.f, 0.f, 0.f};

  const u16* Ap[FM];
  const u16* Bp[FN];
  #pragma unroll
  for (int i = 0; i < FM; i++) {
    int r = m0 + i * 16 + lr;
    if (r > M - 1) r = M - 1;
    Ap[i] = A + (size_t)r * lda + lko;
  }
  #pragma unroll
  for (int j = 0; j < FN; j++) Bp[j] = B + (size_t)(n0 + j * 16 + lr) * ldb + lko;

  #pragma unroll 2
  for (int k0 = 0; k0 < K; k0 += 32) {
    bf16x8 av[FM], bv[FN];
    #pragma unroll
    for (int i = 0; i < FM; i++) av[i] = *(const bf16x8*)(Ap[i] + k0);
    #pragma unroll
    for (int j = 0; j < FN; j++) bv[j] = *(const bf16x8*)(Bp[j] + k0);
    #pragma unroll
    for (int i = 0; i < FM; i++)
      #pragma unroll
      for (int j = 0; j < FN; j++)
        acc[i][j] = __builtin_amdgcn_mfma_f32_16x16x32_bf16(av[i], bv[j], acc[i][j], 0, 0, 0);
  }

  #pragma unroll
  for (int i = 0; i < FM; i++) {
    #pragma unroll
    for (int r = 0; r < 4; r++) {
      int m = m0 + i * 16 + ((lane >> 4) << 2) + r;
      if (m >= M) continue;
      #pragma unroll
      for (int j = 0; j < FN; j++) {
        int n = n0 + j * 16 + lr;
        float v = acc[i][j][r];
        if (bias) v += bias[n];
        if constexpr (ACT == 1) v = fmaxf(v, 0.f);
        if constexpr (ACT == 2) v = sigm(v);
        if constexpr (OUTK == 0) {
          ((float*)Cv)[(size_t)m * ldc + n] = v;
        } else if constexpr (OUTK == 1) {
          ((u16*)Cv)[(size_t)m * ldc + n] = f2bf(v);
        } else {
          if (n < 24) {
            int bb = m / 120, ll = m - bb * 120;
            ((float*)Cv)[(size_t)(bb * 24 + n) * 120 + ll] = v;
          }
        }
      }
    }
  }
}

// ---------------- launch ----------------
extern "C" void kernel_launch(void* const* d_in, const int* in_sizes, int n_in,
                              void* d_out, int out_size, void* d_ws, size_t ws_size,
                              hipStream_t stream) {
  const float* x   = (const float*)d_in[0];
  const float* Ah  = (const float*)d_in[1];
  const float* W1  = (const float*)d_in[2];
  const float* W2  = (const float*)d_in[3];
  const float* Wih = (const float*)d_in[4];
  const float* Whh = (const float*)d_in[5];
  const float* bih = (const float*)d_in[6];
  const float* bhh = (const float*)d_in[7];
  const float* Wh1 = (const float*)d_in[8];
  const float* bh1 = (const float*)d_in[9];
  const float* Wh2 = (const float*)d_in[10];
  const float* bh2 = (const float*)d_in[11];
  const float* Wh3 = (const float*)d_in[12];
  const float* bh3 = (const float*)d_in[13];
  const float* Wh4 = (const float*)d_in[14];
  const float* bh4 = (const float*)d_in[15];
  (void)in_sizes; (void)n_in; (void)out_size;

  char* ws = (char*)d_ws;
  size_t off = 0;
  auto alloc = [&](size_t bytes) -> char* {
    char* p = ws + off;
    off += (bytes + 1023) & ~(size_t)1023;
    return p;
  };

  u16 *gates, *h2c, *Wihp, *Whhp, *Wh1p, *Wh2p, *Wh3p, *Wh4p, *hbuf, *z1, *z2, *z3;
  float *pbuf, *qbuf, *c1, *c2, *biasg, *bh1p, *bh2p, *bh3p, *bh4p, *cbuf;

  auto doplan = [&](int resident) {
    off = 0;
    gates = (u16*)alloc((size_t)resident * 480 * 2048 * 2);
    h2c   = (u16*)alloc((size_t)16 * 480 * 512 * 2);
    pbuf  = (float*)alloc((size_t)192 * 480 * 4);
    qbuf  = (float*)alloc((size_t)192 * 480 * 4);
    c1    = (float*)alloc(512 * 4);
    c2    = (float*)alloc(512 * 4);
    Wihp  = (u16*)alloc((size_t)2048 * 512 * 2);
    Whhp  = (u16*)alloc((size_t)2048 * 512 * 2);
    Wh1p  = (u16*)alloc((size_t)3072 * 512 * 2);
    Wh2p  = (u16*)alloc((size_t)1024 * 3072 * 2);
    Wh3p  = (u16*)alloc((size_t)3072 * 1024 * 2);
    Wh4p  = (u16*)alloc((size_t)128 * 3072 * 2);
    biasg = (float*)alloc(2048 * 4);
    bh1p  = (float*)alloc(3072 * 4);
    bh2p  = (float*)alloc(1024 * 4);
    bh3p  = (float*)alloc(3072 * 4);
    bh4p  = (float*)alloc(128 * 4);
    hbuf  = (u16*)alloc((size_t)480 * 512 * 2);
    cbuf  = (float*)alloc((size_t)480 * 512 * 4);
    z1    = (u16*)alloc((size_t)480 * 3072 * 2);
    z2    = (u16*)alloc((size_t)480 * 1024 * 2);
    z3    = (u16*)alloc((size_t)480 * 3072 * 2);
  };
  doplan(192);
  bool full = (off <= ws_size);
  if (!full) doplan(16);

  // ---- weight packing ----
  packgate_k<<<4096, 256, 0, stream>>>(Wih, Wihp);
  packgate_k<<<4096, 256, 0, stream>>>(Whh, Whhp);
  gatebias_k<<<8, 256, 0, stream>>>(bih, bhh, biasg);
  packT_k<<<6144, 256, 0, stream>>>(Wh1, 500, 3000, Wh1p, 3072, 512);
  packT_k<<<12288, 256, 0, stream>>>(Wh2, 3000, 1000, Wh2p, 1024, 3072);
  packT_k<<<12288, 256, 0, stream>>>(Wh3, 1000, 3000, Wh3p, 3072, 1024);
  packT_k<<<1536, 256, 0, stream>>>(Wh4, 3000, 24, Wh4p, 128, 3072);
  padbias_k<<<12, 256, 0, stream>>>(bh1, 3000, bh1p, 3072);
  padbias_k<<<4, 256, 0, stream>>>(bh2, 1000, bh2p, 1024);
  padbias_k<<<12, 256, 0, stream>>>(bh3, 3000, bh3p, 3072);
  padbias_k<<<1, 256, 0, stream>>>(bh4, 24, bh4p, 128);

  // ---- GCN rank-2 front ----
  c12_k<<<2, 256, 0, stream>>>(W1, W2, c1, c2);
  pq_k<<<768, 128, 0, stream>>>(x, Ah, pbuf, qbuf);

  // ---- gates (chunked h2 materialization + staged GEMM), then LSTM ----
  for (int ci = 0; ci < 12; ci++) {
    int R0 = ci * 7680;
    h2mat_k<<<1920, 256, 0, stream>>>(pbuf, qbuf, c1, c2, h2c, R0);
    u16* Cbase = full ? gates + (size_t)R0 * 2048 : gates;
    gemm_lds_k<<<dim3(16, 60), 256, 0, stream>>>(h2c, Wihp, biasg, Cbase, 7680);
    if (!full) {
      lstm_persist_k<<<30, 256, 0, stream>>>(Whhp, gates, cbuf, hbuf,
                                             ci * 16, ci * 16 + 16, ci * 16);
    }
  }
  if (full) {
    lstm_persist_k<<<30, 256, 0, stream>>>(Whhp, gates, cbuf, hbuf, 0, 192, 0);
  }

  // ---- MLP head ----
  mgemm_k<32, 256, 1, 4, 1, 1><<<dim3(12, 15), 256, 0, stream>>>(
      hbuf, 512, Wh1p, 512, bh1p, z1, 3072, 480, 512);
  mgemm_k<32, 256, 1, 4, 1, 1><<<dim3(4, 15), 256, 0, stream>>>(
      z1, 3072, Wh2p, 3072, bh2p, z2, 1024, 480, 3072);
  mgemm_k<32, 256, 1, 4, 1, 1><<<dim3(12, 15), 256, 0, stream>>>(
      z2, 1024, Wh3p, 1024, bh3p, z3, 3072, 480, 1024);
  mgemm_k<32, 128, 1, 4, 2, 2><<<dim3(1, 15), 256, 0, stream>>>(
      z3, 3072, Wh4p, 3072, bh4p, d_out, 0, 480, 3072);
}

// Round 5
// 9757.192 us; speedup vs baseline: 3.0890x; 3.0890x over previous
//
#include <hip/hip_runtime.h>
#include <stdint.h>

typedef unsigned short u16;
typedef short bf16x8 __attribute__((ext_vector_type(8)));
typedef float f32x4 __attribute__((ext_vector_type(4)));

__device__ __forceinline__ float bf2f(u16 u) {
  union { uint32_t i; float f; } v; v.i = ((uint32_t)u) << 16; return v.f;
}
__device__ __forceinline__ u16 f2bf(float f) {
  union { float f; uint32_t i; } v; v.f = f;
  uint32_t x = v.i;
  return (u16)((x + 0x7FFFu + ((x >> 16) & 1u)) >> 16);
}
__device__ __forceinline__ float sigm(float x) { return 1.f / (1.f + expf(-x)); }

// ---------------- packing ----------------
// Wih/Whh [2000][500] f32 -> [2048][512] bf16, rows interleaved c = j*4+g
__global__ void packgate_k(const float* __restrict__ src, u16* __restrict__ dst) {
  int idx = blockIdx.x * 256 + threadIdx.x;
  if (idx >= 2048 * 512) return;
  int crow = idx >> 9, k = idx & 511;
  int j = crow >> 2, g = crow & 3;
  u16 v = 0;
  if (j < 500 && k < 500) v = f2bf(src[(size_t)(g * 500 + j) * 500 + k]);
  dst[idx] = v;
}

__global__ void gatebias_k(const float* __restrict__ bih, const float* __restrict__ bhh,
                           float* __restrict__ dst) {
  int c = blockIdx.x * 256 + threadIdx.x;
  if (c >= 2048) return;
  int j = c >> 2, g = c & 3;
  dst[c] = (j < 500) ? bih[g * 500 + j] + bhh[g * 500 + j] : 0.f;
}

// src f32 [Ks][Ns] -> dst bf16 [Nd][Kd] (transposed, zero-padded)
__global__ void packT_k(const float* __restrict__ src, int Ks, int Ns,
                        u16* __restrict__ dst, int Nd, int Kd) {
  int idx = blockIdx.x * 256 + threadIdx.x;
  if (idx >= Nd * Kd) return;
  int n = idx / Kd, k = idx - n * Kd;
  dst[idx] = (n < Ns && k < Ks) ? f2bf(src[(size_t)k * Ns + n]) : (u16)0;
}

__global__ void padbias_k(const float* __restrict__ s, int Ns, float* __restrict__ dst, int Nd) {
  int i = blockIdx.x * 256 + threadIdx.x;
  if (i >= Nd) return;
  dst[i] = (i < Ns) ? s[i] : 0.f;
}

__global__ void zero_k(uint32_t* __restrict__ p, int n) {
  int i = blockIdx.x * 256 + threadIdx.x;
  if (i < n) p[i] = 0u;
}

// ---------------- c1 = W2^T W1+, c2 = W2^T W1- ----------------
__global__ void c12_k(const float* __restrict__ W1, const float* __restrict__ W2,
                      float* __restrict__ c1, float* __restrict__ c2) {
  int f = blockIdx.x * 256 + threadIdx.x;
  if (f >= 512) return;
  float s1 = 0.f, s2 = 0.f;
  if (f < 500) {
    for (int g = 0; g < 500; g++) {
      float w = W1[g];
      float v = W2[(size_t)g * 500 + f];
      s1 = fmaf(fmaxf(w, 0.f), v, s1);
      s2 = fmaf(fminf(w, 0.f), v, s2);
    }
  }
  c1[f] = s1; c2[f] = s2;
}

// ---------------- p = A@(A@x)+, q = A@(A@x)- ----------------
__global__ void pq_k(const float* __restrict__ x, const float* __restrict__ A,
                     float* __restrict__ p, float* __restrict__ q) {
  __shared__ float xs[120], axp[120], axm[120];
  int bt = blockIdx.x, tid = threadIdx.x;
  int t = bt >> 2, b = bt & 3;
  if (tid < 120) xs[tid] = x[(size_t)(b * 192 + t) * 120 + tid];
  __syncthreads();
  if (tid < 120) {
    const float* Ar = A + tid * 120;
    float s = 0.f;
    for (int j = 0; j < 120; j++) s = fmaf(Ar[j], xs[j], s);
    axp[tid] = fmaxf(s, 0.f);
    axm[tid] = fminf(s, 0.f);
  }
  __syncthreads();
  if (tid < 120) {
    const float* Ar = A + tid * 120;
    float sp = 0.f, sm = 0.f;
    for (int j = 0; j < 120; j++) { float a = Ar[j]; sp = fmaf(a, axp[j], sp); sm = fmaf(a, axm[j], sm); }
    int o = t * 480 + b * 120 + tid;
    p[o] = sp; q[o] = sm;
  }
}

// ---------------- h2 = relu(p*c1 + q*c2), bf16 rows ----------------
__global__ void h2mat_k(const float* __restrict__ p, const float* __restrict__ q,
                        const float* __restrict__ c1, const float* __restrict__ c2,
                        u16* __restrict__ h2c, int R0) {
  int row = blockIdx.x * 4 + (threadIdx.x >> 6);
  int go = (threadIdx.x & 63) * 8;
  float pv = p[R0 + row], qv = q[R0 + row];
  alignas(16) u16 o[8];
  #pragma unroll
  for (int i = 0; i < 8; i++) {
    float v = pv * c1[go + i] + qv * c2[go + i];
    o[i] = f2bf(fmaxf(v, 0.f));
  }
  *(uint4*)&h2c[(size_t)row * 512 + go] = *(const uint4*)o;
}

// ---------------- LDS-staged gates GEMM: C = A @ B^T + bias (bf16 out) ----------------
__global__ __launch_bounds__(256, 2) void gemm_lds_k(
    const u16* __restrict__ A, const u16* __restrict__ B,
    const float* __restrict__ bias, u16* __restrict__ C, int M) {
  __shared__ u16 Al[2][128][32];
  __shared__ u16 Bl[2][128][32];
  const int tid = threadIdx.x, wid = tid >> 6, lane = tid & 63;
  const int lr = lane & 15, g4 = lane >> 4;
  const int m0 = blockIdx.y * 128, n0 = blockIdx.x * 128;
  const int ms = (wid & 1) * 64, ns = (wid >> 1) * 64;
  const int srow = tid >> 1, shalf = (tid & 1) * 16;
  const u16* Asrc = A + (size_t)(m0 + srow) * 512 + shalf;
  const u16* Bsrc = B + (size_t)(n0 + srow) * 512 + shalf;

  f32x4 acc[4][4];
  #pragma unroll
  for (int i = 0; i < 4; i++)
    #pragma unroll
    for (int j = 0; j < 4; j++) acc[i][j] = (f32x4){0.f, 0.f, 0.f, 0.f};

  uint4 ra0, ra1, rb0, rb1;
  ra0 = *(const uint4*)(Asrc + 0);  ra1 = *(const uint4*)(Asrc + 8);
  rb0 = *(const uint4*)(Bsrc + 0);  rb1 = *(const uint4*)(Bsrc + 8);
  *(uint4*)&Al[0][srow][shalf] = ra0; *(uint4*)&Al[0][srow][shalf + 8] = ra1;
  *(uint4*)&Bl[0][srow][shalf] = rb0; *(uint4*)&Bl[0][srow][shalf + 8] = rb1;
  ra0 = *(const uint4*)(Asrc + 32); ra1 = *(const uint4*)(Asrc + 40);
  rb0 = *(const uint4*)(Bsrc + 32); rb1 = *(const uint4*)(Bsrc + 40);
  __syncthreads();

  #pragma unroll
  for (int kt = 0; kt < 16; kt++) {
    const int cur = kt & 1;
    if (kt < 15) {
      *(uint4*)&Al[cur ^ 1][srow][shalf] = ra0; *(uint4*)&Al[cur ^ 1][srow][shalf + 8] = ra1;
      *(uint4*)&Bl[cur ^ 1][srow][shalf] = rb0; *(uint4*)&Bl[cur ^ 1][srow][shalf + 8] = rb1;
    }
    if (kt < 14) {
      ra0 = *(const uint4*)(Asrc + (kt + 2) * 32);     ra1 = *(const uint4*)(Asrc + (kt + 2) * 32 + 8);
      rb0 = *(const uint4*)(Bsrc + (kt + 2) * 32);     rb1 = *(const uint4*)(Bsrc + (kt + 2) * 32 + 8);
    }
    bf16x8 av[4], bv[4];
    #pragma unroll
    for (int i = 0; i < 4; i++) av[i] = *(const bf16x8*)&Al[cur][ms + i * 16 + lr][g4 * 8];
    #pragma unroll
    for (int j = 0; j < 4; j++) bv[j] = *(const bf16x8*)&Bl[cur][ns + j * 16 + lr][g4 * 8];
    #pragma unroll
    for (int i = 0; i < 4; i++)
      #pragma unroll
      for (int j = 0; j < 4; j++)
        acc[i][j] = __builtin_amdgcn_mfma_f32_16x16x32_bf16(av[i], bv[j], acc[i][j], 0, 0, 0);
    __syncthreads();
  }

  #pragma unroll
  for (int i = 0; i < 4; i++)
    #pragma unroll
    for (int r = 0; r < 4; r++) {
      int m = m0 + ms + i * 16 + g4 * 4 + r;
      #pragma unroll
      for (int j = 0; j < 4; j++) {
        int n = n0 + ns + j * 16 + lr;
        C[(size_t)m * 2048 + n] = f2bf(acc[i][j][r] + bias[n]);
      }
    }
}

// ---------------- device-barrier persistent LSTM, Whh register-stationary ----------------
// 240 blocks = 15 m-tiles x 16 n-slices. Whh slice [32 cols][512] in VGPRs per wave.
// h parity-buffered in hbuf[2][480][512] bf16; c in VGPRs (persisted to cbuf).
// ctr[t]: monotonic arrival counter per step (pre-zeroed).
__global__ __launch_bounds__(256, 1) void lstm_gridsync_k(
    const u16* __restrict__ Whh, const u16* __restrict__ gates,
    u16* __restrict__ hbuf, float* __restrict__ cbuf,
    unsigned* __restrict__ ctr, int t0, int t1) {
  __shared__ u16 hls[32][520];
  const int tid = threadIdx.x, wid = tid >> 6, lane = tid & 63;
  const int lr = lane & 15, g4 = lane >> 4;
  const int bx = blockIdx.x;
  const int m0 = (bx >> 4) * 32;
  const int ns = bx & 15;
  const int colbase = ns * 128 + wid * 32;
  const int jbase = ns * 32 + wid * 8;

  // Whh slice -> registers (stationary across all steps)
  bf16x8 bv[2][16];
  #pragma unroll
  for (int nt = 0; nt < 2; nt++)
    #pragma unroll
    for (int kk = 0; kk < 16; kk++)
      bv[nt][kk] = *(const bf16x8*)(Whh + (size_t)(colbase + nt * 16 + lr) * 512 + kk * 32 + g4 * 8);

  float c[2][2];
  #pragma unroll
  for (int mt = 0; mt < 2; mt++)
    #pragma unroll
    for (int nt = 0; nt < 2; nt++)
      c[mt][nt] = cbuf[(size_t)(m0 + mt * 16 + lr) * 512 + jbase + nt * 4 + g4];

  for (int t = t0; t < t1; ++t) {
    // fill LDS h-tile (h_{t-1}) from parity buffer
    const u16* hsrc = hbuf + ((t + 1) & 1) * (480 * 512);
    #pragma unroll
    for (int i = 0; i < 8; i++) {
      int e = i * 256 + tid;
      int row = e >> 6, col = (e & 63) * 8;
      uint4 v = *(const uint4*)(hsrc + (size_t)(m0 + row) * 512 + col);
      *(uint4*)&hls[row][col] = v;
    }
    // gates quads for this step (ready long before; hides under fill+mfma)
    const u16* gsrc = gates + (size_t)(t - t0) * 480 * 2048;
    uint2 gq[2][2];
    #pragma unroll
    for (int mt = 0; mt < 2; mt++)
      #pragma unroll
      for (int nt = 0; nt < 2; nt++)
        gq[mt][nt] = *(const uint2*)(gsrc + (size_t)(m0 + mt * 16 + lr) * 2048 + colbase + nt * 16 + g4 * 4);
    __syncthreads();

    f32x4 acc[2][2];
    #pragma unroll
    for (int mt = 0; mt < 2; mt++)
      #pragma unroll
      for (int nt = 0; nt < 2; nt++) acc[mt][nt] = (f32x4){0.f, 0.f, 0.f, 0.f};
    #pragma unroll
    for (int kk = 0; kk < 16; kk++) {
      bf16x8 av0 = *(const bf16x8*)&hls[lr][kk * 32 + g4 * 8];
      bf16x8 av1 = *(const bf16x8*)&hls[16 + lr][kk * 32 + g4 * 8];
      acc[0][0] = __builtin_amdgcn_mfma_f32_16x16x32_bf16(bv[0][kk], av0, acc[0][0], 0, 0, 0);
      acc[0][1] = __builtin_amdgcn_mfma_f32_16x16x32_bf16(bv[1][kk], av0, acc[0][1], 0, 0, 0);
      acc[1][0] = __builtin_amdgcn_mfma_f32_16x16x32_bf16(bv[0][kk], av1, acc[1][0], 0, 0, 0);
      acc[1][1] = __builtin_amdgcn_mfma_f32_16x16x32_bf16(bv[1][kk], av1, acc[1][1], 0, 0, 0);
    }

    // cell (lane-local quads) + h scatter to parity buffer
    u16* hdst = hbuf + (t & 1) * (480 * 512);
    #pragma unroll
    for (int mt = 0; mt < 2; mt++)
      #pragma unroll
      for (int nt = 0; nt < 2; nt++) {
        const u16* gp = (const u16*)&gq[mt][nt];
        float gi = bf2f(gp[0]) + acc[mt][nt][0];
        float gf = bf2f(gp[1]) + acc[mt][nt][1];
        float gg = bf2f(gp[2]) + acc[mt][nt][2];
        float go = bf2f(gp[3]) + acc[mt][nt][3];
        float cn = sigm(gf) * c[mt][nt] + sigm(gi) * tanhf(gg);
        c[mt][nt] = cn;
        hdst[(size_t)(m0 + mt * 16 + lr) * 512 + jbase + nt * 4 + g4] = f2bf(sigm(go) * tanhf(cn));
      }

    // device-wide barrier for step t
    __threadfence();
    __syncthreads();
    if (tid == 0) {
      __hip_atomic_fetch_add(&ctr[t], 1u, __ATOMIC_RELAXED, __HIP_MEMORY_SCOPE_AGENT);
      while (__hip_atomic_load(&ctr[t], __ATOMIC_RELAXED, __HIP_MEMORY_SCOPE_AGENT) < 240u)
        __builtin_amdgcn_s_sleep(2);
    }
    __syncthreads();
    __threadfence();
  }

  // persist c for next dispatch
  #pragma unroll
  for (int mt = 0; mt < 2; mt++)
    #pragma unroll
    for (int nt = 0; nt < 2; nt++)
      cbuf[(size_t)(m0 + mt * 16 + lr) * 512 + jbase + nt * 4 + g4] = c[mt][nt];
}

// ---------------- direct MFMA GEMM (MLP head) ----------------
template<int BM, int BN, int WM, int WN, int ACT, int OUTK>
__global__ __launch_bounds__(256) void mgemm_k(
    const u16* __restrict__ A, int lda,
    const u16* __restrict__ B, int ldb,
    const float* __restrict__ bias,
    void* __restrict__ Cv, int ldc, int M, int K) {
  constexpr int FM = BM / (WM * 16), FN = BN / (WN * 16);
  const int tid = threadIdx.x;
  const int wid = tid >> 6, lane = tid & 63;
  const int lr = lane & 15, lko = (lane >> 4) << 3;
  const int m0 = blockIdx.y * BM + (wid % WM) * (FM * 16);
  const int n0 = blockIdx.x * BN + (wid / WM) * (FN * 16);

  f32x4 acc[FM][FN];
  #pragma unroll
  for (int i = 0; i < FM; i++)
    #pragma unroll
    for (int j = 0; j < FN; j++) acc[i][j] = (f32x4){0.f, 0.f, 0.f, 0.f};

  const u16* Ap[FM];
  const u16* Bp[FN];
  #pragma unroll
  for (int i = 0; i < FM; i++) {
    int r = m0 + i * 16 + lr;
    if (r > M - 1) r = M - 1;
    Ap[i] = A + (size_t)r * lda + lko;
  }
  #pragma unroll
  for (int j = 0; j < FN; j++) Bp[j] = B + (size_t)(n0 + j * 16 + lr) * ldb + lko;

  #pragma unroll 2
  for (int k0 = 0; k0 < K; k0 += 32) {
    bf16x8 av[FM], bv[FN];
    #pragma unroll
    for (int i = 0; i < FM; i++) av[i] = *(const bf16x8*)(Ap[i] + k0);
    #pragma unroll
    for (int j = 0; j < FN; j++) bv[j] = *(const bf16x8*)(Bp[j] + k0);
    #pragma unroll
    for (int i = 0; i < FM; i++)
      #pragma unroll
      for (int j = 0; j < FN; j++)
        acc[i][j] = __builtin_amdgcn_mfma_f32_16x16x32_bf16(av[i], bv[j], acc[i][j], 0, 0, 0);
  }

  #pragma unroll
  for (int i = 0; i < FM; i++) {
    #pragma unroll
    for (int r = 0; r < 4; r++) {
      int m = m0 + i * 16 + ((lane >> 4) << 2) + r;
      if (m >= M) continue;
      #pragma unroll
      for (int j = 0; j < FN; j++) {
        int n = n0 + j * 16 + lr;
        float v = acc[i][j][r];
        if (bias) v += bias[n];
        if constexpr (ACT == 1) v = fmaxf(v, 0.f);
        if constexpr (ACT == 2) v = sigm(v);
        if constexpr (OUTK == 0) {
          ((float*)Cv)[(size_t)m * ldc + n] = v;
        } else if constexpr (OUTK == 1) {
          ((u16*)Cv)[(size_t)m * ldc + n] = f2bf(v);
        } else {
          if (n < 24) {
            int bb = m / 120, ll = m - bb * 120;
            ((float*)Cv)[(size_t)(bb * 24 + n) * 120 + ll] = v;
          }
        }
      }
    }
  }
}

// ---------------- launch ----------------
extern "C" void kernel_launch(void* const* d_in, const int* in_sizes, int n_in,
                              void* d_out, int out_size, void* d_ws, size_t ws_size,
                              hipStream_t stream) {
  const float* x   = (const float*)d_in[0];
  const float* Ah  = (const float*)d_in[1];
  const float* W1  = (const float*)d_in[2];
  const float* W2  = (const float*)d_in[3];
  const float* Wih = (const float*)d_in[4];
  const float* Whh = (const float*)d_in[5];
  const float* bih = (const float*)d_in[6];
  const float* bhh = (const float*)d_in[7];
  const float* Wh1 = (const float*)d_in[8];
  const float* bh1 = (const float*)d_in[9];
  const float* Wh2 = (const float*)d_in[10];
  const float* bh2 = (const float*)d_in[11];
  const float* Wh3 = (const float*)d_in[12];
  const float* bh3 = (const float*)d_in[13];
  const float* Wh4 = (const float*)d_in[14];
  const float* bh4 = (const float*)d_in[15];
  (void)in_sizes; (void)n_in; (void)out_size;

  char* ws = (char*)d_ws;
  size_t off = 0;
  auto alloc = [&](size_t bytes) -> char* {
    char* p = ws + off;
    off += (bytes + 1023) & ~(size_t)1023;
    return p;
  };

  u16 *gates, *h2c, *Wihp, *Whhp, *Wh1p, *Wh2p, *Wh3p, *Wh4p, *hbuf, *z1, *z2, *z3;
  float *pbuf, *qbuf, *c1, *c2, *biasg, *bh1p, *bh2p, *bh3p, *bh4p, *cbuf;
  unsigned* ctr;

  auto doplan = [&](int res) {
    off = 0;
    gates = (u16*)alloc((size_t)res * 480 * 2048 * 2);
    h2c   = (u16*)alloc((size_t)res * 480 * 512 * 2);
    pbuf  = (float*)alloc((size_t)192 * 480 * 4);
    qbuf  = (float*)alloc((size_t)192 * 480 * 4);
    c1    = (float*)alloc(512 * 4);
    c2    = (float*)alloc(512 * 4);
    Wihp  = (u16*)alloc((size_t)2048 * 512 * 2);
    Whhp  = (u16*)alloc((size_t)2048 * 512 * 2);
    Wh1p  = (u16*)alloc((size_t)3072 * 512 * 2);
    Wh2p  = (u16*)alloc((size_t)1024 * 3072 * 2);
    Wh3p  = (u16*)alloc((size_t)3072 * 1024 * 2);
    Wh4p  = (u16*)alloc((size_t)128 * 3072 * 2);
    biasg = (float*)alloc(2048 * 4);
    bh1p  = (float*)alloc(3072 * 4);
    bh2p  = (float*)alloc(1024 * 4);
    bh3p  = (float*)alloc(3072 * 4);
    bh4p  = (float*)alloc(128 * 4);
    // hbuf(2 parity) + cbuf + ctr contiguous -> zeroed in one kernel
    hbuf  = (u16*)alloc((size_t)2 * 480 * 512 * 2);
    cbuf  = (float*)alloc((size_t)480 * 512 * 4);
    ctr   = (unsigned*)alloc(1024);
    z1    = (u16*)alloc((size_t)480 * 3072 * 2);
    z2    = (u16*)alloc((size_t)480 * 1024 * 2);
    z3    = (u16*)alloc((size_t)480 * 3072 * 2);
  };
  int RES = 192; doplan(RES);
  if (off > ws_size) { RES = 96; doplan(RES); }
  if (off > ws_size) { RES = 48; doplan(RES); }
  if (off > ws_size) { RES = 16; doplan(RES); }

  // ---- weight packing ----
  packgate_k<<<4096, 256, 0, stream>>>(Wih, Wihp);
  packgate_k<<<4096, 256, 0, stream>>>(Whh, Whhp);
  gatebias_k<<<8, 256, 0, stream>>>(bih, bhh, biasg);
  packT_k<<<6144, 256, 0, stream>>>(Wh1, 500, 3000, Wh1p, 3072, 512);
  packT_k<<<12288, 256, 0, stream>>>(Wh2, 3000, 1000, Wh2p, 1024, 3072);
  packT_k<<<12288, 256, 0, stream>>>(Wh3, 1000, 3000, Wh3p, 3072, 1024);
  packT_k<<<1536, 256, 0, stream>>>(Wh4, 3000, 24, Wh4p, 128, 3072);
  padbias_k<<<12, 256, 0, stream>>>(bh1, 3000, bh1p, 3072);
  padbias_k<<<4, 256, 0, stream>>>(bh2, 1000, bh2p, 1024);
  padbias_k<<<12, 256, 0, stream>>>(bh3, 3000, bh3p, 3072);
  padbias_k<<<1, 256, 0, stream>>>(bh4, 24, bh4p, 128);

  // ---- GCN rank-2 front ----
  c12_k<<<2, 256, 0, stream>>>(W1, W2, c1, c2);
  pq_k<<<768, 128, 0, stream>>>(x, Ah, pbuf, qbuf);

  // zero hbuf(2x) + cbuf + ctr: contiguous 983040 + 983040 + 1024 = 1967104 B
  zero_k<<<1921, 256, 0, stream>>>((uint32_t*)hbuf, 491776);

  const int NCH = 192 / RES;
  for (int ci = 0; ci < NCH; ci++) {
    int t0 = ci * RES;
    int M = RES * 480;
    h2mat_k<<<M / 4, 256, 0, stream>>>(pbuf, qbuf, c1, c2, h2c, t0 * 480);
    gemm_lds_k<<<dim3(16, M / 128), 256, 0, stream>>>(h2c, Wihp, biasg, gates, M);
    lstm_gridsync_k<<<240, 256, 0, stream>>>(Whhp, gates, hbuf, cbuf, ctr, t0, t0 + RES);
  }

  // ---- MLP head: h_last = hbuf parity 1 (t=191 odd) ----
  const u16* hlast = hbuf + 480 * 512;
  mgemm_k<32, 256, 1, 4, 1, 1><<<dim3(12, 15), 256, 0, stream>>>(
      hlast, 512, Wh1p, 512, bh1p, z1, 3072, 480, 512);
  mgemm_k<32, 256, 1, 4, 1, 1><<<dim3(4, 15), 256, 0, stream>>>(
      z1, 3072, Wh2p, 3072, bh2p, z2, 1024, 480, 3072);
  mgemm_k<32, 256, 1, 4, 1, 1><<<dim3(12, 15), 256, 0, stream>>>(
      z2, 1024, Wh3p, 1024, bh3p, z3, 3072, 480, 1024);
  mgemm_k<32, 128, 1, 4, 2, 2><<<dim3(1, 15), 256, 0, stream>>>(
      z3, 3072, Wh4p, 3072, bh4p, d_out, 0, 480, 3072);
}

// Round 6
// 2361.173 us; speedup vs baseline: 12.7649x; 4.1323x over previous
//
#include <hip/hip_runtime.h>
#include <stdint.h>

typedef unsigned short u16;
typedef unsigned long long u64;
typedef short bf16x8 __attribute__((ext_vector_type(8)));
typedef float f32x4 __attribute__((ext_vector_type(4)));

__device__ __forceinline__ float bf2f(u16 u) {
  union { uint32_t i; float f; } v; v.i = ((uint32_t)u) << 16; return v.f;
}
__device__ __forceinline__ u16 f2bf(float f) {
  union { float f; uint32_t i; } v; v.f = f;
  uint32_t x = v.i;
  return (u16)((x + 0x7FFFu + ((x >> 16) & 1u)) >> 16);
}
__device__ __forceinline__ float sigm(float x) { return 1.f / (1.f + expf(-x)); }

// ---------------- packing ----------------
// Wih/Whh [2000][500] f32 -> [2048][512] bf16, rows interleaved c = j*4+g
__global__ void packgate_k(const float* __restrict__ src, u16* __restrict__ dst) {
  int idx = blockIdx.x * 256 + threadIdx.x;
  if (idx >= 2048 * 512) return;
  int crow = idx >> 9, k = idx & 511;
  int j = crow >> 2, g = crow & 3;
  u16 v = 0;
  if (j < 500 && k < 500) v = f2bf(src[(size_t)(g * 500 + j) * 500 + k]);
  dst[idx] = v;
}

__global__ void gatebias_k(const float* __restrict__ bih, const float* __restrict__ bhh,
                           float* __restrict__ dst) {
  int c = blockIdx.x * 256 + threadIdx.x;
  if (c >= 2048) return;
  int j = c >> 2, g = c & 3;
  dst[c] = (j < 500) ? bih[g * 500 + j] + bhh[g * 500 + j] : 0.f;
}

// src f32 [Ks][Ns] -> dst bf16 [Nd][Kd] (transposed, zero-padded)
__global__ void packT_k(const float* __restrict__ src, int Ks, int Ns,
                        u16* __restrict__ dst, int Nd, int Kd) {
  int idx = blockIdx.x * 256 + threadIdx.x;
  if (idx >= Nd * Kd) return;
  int n = idx / Kd, k = idx - n * Kd;
  dst[idx] = (n < Ns && k < Ks) ? f2bf(src[(size_t)k * Ns + n]) : (u16)0;
}

__global__ void padbias_k(const float* __restrict__ s, int Ns, float* __restrict__ dst, int Nd) {
  int i = blockIdx.x * 256 + threadIdx.x;
  if (i >= Nd) return;
  dst[i] = (i < Ns) ? s[i] : 0.f;
}

__global__ void zero_k(uint32_t* __restrict__ p, int n) {
  int i = blockIdx.x * 256 + threadIdx.x;
  if (i < n) p[i] = 0u;
}

// ---------------- c1 = W2^T W1+, c2 = W2^T W1- ----------------
__global__ void c12_k(const float* __restrict__ W1, const float* __restrict__ W2,
                      float* __restrict__ c1, float* __restrict__ c2) {
  int f = blockIdx.x * 256 + threadIdx.x;
  if (f >= 512) return;
  float s1 = 0.f, s2 = 0.f;
  if (f < 500) {
    for (int g = 0; g < 500; g++) {
      float w = W1[g];
      float v = W2[(size_t)g * 500 + f];
      s1 = fmaf(fmaxf(w, 0.f), v, s1);
      s2 = fmaf(fminf(w, 0.f), v, s2);
    }
  }
  c1[f] = s1; c2[f] = s2;
}

// ---------------- p = A@(A@x)+, q = A@(A@x)- ----------------
__global__ void pq_k(const float* __restrict__ x, const float* __restrict__ A,
                     float* __restrict__ p, float* __restrict__ q) {
  __shared__ float xs[120], axp[120], axm[120];
  int bt = blockIdx.x, tid = threadIdx.x;
  int t = bt >> 2, b = bt & 3;
  if (tid < 120) xs[tid] = x[(size_t)(b * 192 + t) * 120 + tid];
  __syncthreads();
  if (tid < 120) {
    const float* Ar = A + tid * 120;
    float s = 0.f;
    for (int j = 0; j < 120; j++) s = fmaf(Ar[j], xs[j], s);
    axp[tid] = fmaxf(s, 0.f);
    axm[tid] = fminf(s, 0.f);
  }
  __syncthreads();
  if (tid < 120) {
    const float* Ar = A + tid * 120;
    float sp = 0.f, sm = 0.f;
    for (int j = 0; j < 120; j++) { float a = Ar[j]; sp = fmaf(a, axp[j], sp); sm = fmaf(a, axm[j], sm); }
    int o = t * 480 + b * 120 + tid;
    p[o] = sp; q[o] = sm;
  }
}

// ---------------- h2 = relu(p*c1 + q*c2), bf16 rows ----------------
__global__ void h2mat_k(const float* __restrict__ p, const float* __restrict__ q,
                        const float* __restrict__ c1, const float* __restrict__ c2,
                        u16* __restrict__ h2c, int R0) {
  int row = blockIdx.x * 4 + (threadIdx.x >> 6);
  int go = (threadIdx.x & 63) * 8;
  float pv = p[R0 + row], qv = q[R0 + row];
  alignas(16) u16 o[8];
  #pragma unroll
  for (int i = 0; i < 8; i++) {
    float v = pv * c1[go + i] + qv * c2[go + i];
    o[i] = f2bf(fmaxf(v, 0.f));
  }
  *(uint4*)&h2c[(size_t)row * 512 + go] = *(const uint4*)o;
}

// ---------------- LDS-staged gates GEMM: C = A @ B^T + bias (bf16 out) ----------------
__global__ __launch_bounds__(256, 2) void gemm_lds_k(
    const u16* __restrict__ A, const u16* __restrict__ B,
    const float* __restrict__ bias, u16* __restrict__ C, int M) {
  __shared__ u16 Al[2][128][32];
  __shared__ u16 Bl[2][128][32];
  const int tid = threadIdx.x, wid = tid >> 6, lane = tid & 63;
  const int lr = lane & 15, g4 = lane >> 4;
  const int m0 = blockIdx.y * 128, n0 = blockIdx.x * 128;
  const int ms = (wid & 1) * 64, ns = (wid >> 1) * 64;
  const int srow = tid >> 1, shalf = (tid & 1) * 16;
  const u16* Asrc = A + (size_t)(m0 + srow) * 512 + shalf;
  const u16* Bsrc = B + (size_t)(n0 + srow) * 512 + shalf;

  f32x4 acc[4][4];
  #pragma unroll
  for (int i = 0; i < 4; i++)
    #pragma unroll
    for (int j = 0; j < 4; j++) acc[i][j] = (f32x4){0.f, 0.f, 0.f, 0.f};

  uint4 ra0, ra1, rb0, rb1;
  ra0 = *(const uint4*)(Asrc + 0);  ra1 = *(const uint4*)(Asrc + 8);
  rb0 = *(const uint4*)(Bsrc + 0);  rb1 = *(const uint4*)(Bsrc + 8);
  *(uint4*)&Al[0][srow][shalf] = ra0; *(uint4*)&Al[0][srow][shalf + 8] = ra1;
  *(uint4*)&Bl[0][srow][shalf] = rb0; *(uint4*)&Bl[0][srow][shalf + 8] = rb1;
  ra0 = *(const uint4*)(Asrc + 32); ra1 = *(const uint4*)(Asrc + 40);
  rb0 = *(const uint4*)(Bsrc + 32); rb1 = *(const uint4*)(Bsrc + 40);
  __syncthreads();

  #pragma unroll
  for (int kt = 0; kt < 16; kt++) {
    const int cur = kt & 1;
    if (kt < 15) {
      *(uint4*)&Al[cur ^ 1][srow][shalf] = ra0; *(uint4*)&Al[cur ^ 1][srow][shalf + 8] = ra1;
      *(uint4*)&Bl[cur ^ 1][srow][shalf] = rb0; *(uint4*)&Bl[cur ^ 1][srow][shalf + 8] = rb1;
    }
    if (kt < 14) {
      ra0 = *(const uint4*)(Asrc + (kt + 2) * 32);     ra1 = *(const uint4*)(Asrc + (kt + 2) * 32 + 8);
      rb0 = *(const uint4*)(Bsrc + (kt + 2) * 32);     rb1 = *(const uint4*)(Bsrc + (kt + 2) * 32 + 8);
    }
    bf16x8 av[4], bv[4];
    #pragma unroll
    for (int i = 0; i < 4; i++) av[i] = *(const bf16x8*)&Al[cur][ms + i * 16 + lr][g4 * 8];
    #pragma unroll
    for (int j = 0; j < 4; j++) bv[j] = *(const bf16x8*)&Bl[cur][ns + j * 16 + lr][g4 * 8];
    #pragma unroll
    for (int i = 0; i < 4; i++)
      #pragma unroll
      for (int j = 0; j < 4; j++)
        acc[i][j] = __builtin_amdgcn_mfma_f32_16x16x32_bf16(av[i], bv[j], acc[i][j], 0, 0, 0);
    __syncthreads();
  }

  #pragma unroll
  for (int i = 0; i < 4; i++)
    #pragma unroll
    for (int r = 0; r < 4; r++) {
      int m = m0 + ms + i * 16 + g4 * 4 + r;
      #pragma unroll
      for (int j = 0; j < 4; j++) {
        int n = n0 + ns + j * 16 + lr;
        C[(size_t)m * 2048 + n] = f2bf(acc[i][j][r] + bias[n]);
      }
    }
}

// ---------------- flag-synced persistent LSTM, Whh register-stationary ----------------
// 240 blocks = 15 m-tiles x 16 n-slices. NO __threadfence: h exchanged via
// device-scope relaxed atomic u64 stores/loads (single-instr, L2-bypass, no wbinv);
// per-(t, m-tile) arrival counters (16 producers each), monotonic, pre-zeroed.
__global__ __launch_bounds__(256, 1) void lstm_flag_k(
    const u16* __restrict__ Whh, const u16* __restrict__ gates,
    u16* __restrict__ hbuf, float* __restrict__ cbuf,
    unsigned* __restrict__ ctr, int t0, int t1) {
  __shared__ u16 hls[32][520];
  __shared__ u16 hout[32][36];
  const int tid = threadIdx.x, wid = tid >> 6, lane = tid & 63;
  const int lr = lane & 15, g4 = lane >> 4;
  const int bx = blockIdx.x;
  const int mt = bx >> 4, ns = bx & 15;
  const int m0 = mt * 32;
  const int colbase = ns * 128 + wid * 32;
  const int jbase = ns * 32 + wid * 8;

  // Whh slice -> registers (stationary across all steps)
  bf16x8 bv[2][16];
  #pragma unroll
  for (int nt = 0; nt < 2; nt++)
    #pragma unroll
    for (int kk = 0; kk < 16; kk++)
      bv[nt][kk] = *(const bf16x8*)(Whh + (size_t)(colbase + nt * 16 + lr) * 512 + kk * 32 + g4 * 8);

  float c[2][2];
  #pragma unroll
  for (int m2 = 0; m2 < 2; m2++)
    #pragma unroll
    for (int nt = 0; nt < 2; nt++)
      c[m2][nt] = cbuf[(size_t)(m0 + m2 * 16 + lr) * 512 + jbase + nt * 4 + g4];

  for (int t = t0; t < t1; ++t) {
    // wait for my m-tile's h_{t-1} producers (skip at dispatch boundary: kernel
    // boundary is a full coherence point)
    if (t > t0) {
      if (tid == 0) {
        while (__hip_atomic_load(&ctr[(t - 1) * 15 + mt], __ATOMIC_RELAXED,
                                 __HIP_MEMORY_SCOPE_AGENT) < 16u)
          __builtin_amdgcn_s_sleep(1);
      }
      __syncthreads();
    }
    // fill LDS h-tile (32 rows x 512 cols) via device-coherent u64 loads
    const u16* hsrc = hbuf + ((t + 1) & 1) * (480 * 512);
    #pragma unroll
    for (int half = 0; half < 2; half++) {
      u64 vf[8];
      #pragma unroll
      for (int k = 0; k < 8; k++) {
        int i = (half * 8 + k) * 256 + tid;
        int row = i >> 7, col8 = i & 127;
        const u64* p = (const u64*)(hsrc + (size_t)(m0 + row) * 512) + col8;
        vf[k] = __hip_atomic_load(p, __ATOMIC_RELAXED, __HIP_MEMORY_SCOPE_AGENT);
      }
      #pragma unroll
      for (int k = 0; k < 8; k++) {
        int i = (half * 8 + k) * 256 + tid;
        int row = i >> 7, col8 = i & 127;
        *(u64*)&hls[row][col8 * 4] = vf[k];
      }
    }
    // gates quads for this step
    const u16* gsrc = gates + (size_t)(t - t0) * 480 * 2048;
    uint2 gq[2][2];
    #pragma unroll
    for (int m2 = 0; m2 < 2; m2++)
      #pragma unroll
      for (int nt = 0; nt < 2; nt++)
        gq[m2][nt] = *(const uint2*)(gsrc + (size_t)(m0 + m2 * 16 + lr) * 2048 + colbase + nt * 16 + g4 * 4);
    __syncthreads();

    f32x4 acc[2][2];
    #pragma unroll
    for (int m2 = 0; m2 < 2; m2++)
      #pragma unroll
      for (int nt = 0; nt < 2; nt++) acc[m2][nt] = (f32x4){0.f, 0.f, 0.f, 0.f};
    #pragma unroll
    for (int kk = 0; kk < 16; kk++) {
      bf16x8 av0 = *(const bf16x8*)&hls[lr][kk * 32 + g4 * 8];
      bf16x8 av1 = *(const bf16x8*)&hls[16 + lr][kk * 32 + g4 * 8];
      acc[0][0] = __builtin_amdgcn_mfma_f32_16x16x32_bf16(bv[0][kk], av0, acc[0][0], 0, 0, 0);
      acc[0][1] = __builtin_amdgcn_mfma_f32_16x16x32_bf16(bv[1][kk], av0, acc[0][1], 0, 0, 0);
      acc[1][0] = __builtin_amdgcn_mfma_f32_16x16x32_bf16(bv[0][kk], av1, acc[1][0], 0, 0, 0);
      acc[1][1] = __builtin_amdgcn_mfma_f32_16x16x32_bf16(bv[1][kk], av1, acc[1][1], 0, 0, 0);
    }

    // cell (lane-local quads) -> LDS pack
    #pragma unroll
    for (int m2 = 0; m2 < 2; m2++)
      #pragma unroll
      for (int nt = 0; nt < 2; nt++) {
        const u16* gp = (const u16*)&gq[m2][nt];
        float gi = bf2f(gp[0]) + acc[m2][nt][0];
        float gf = bf2f(gp[1]) + acc[m2][nt][1];
        float gg = bf2f(gp[2]) + acc[m2][nt][2];
        float go = bf2f(gp[3]) + acc[m2][nt][3];
        float cn = sigm(gf) * c[m2][nt] + sigm(gi) * tanhf(gg);
        c[m2][nt] = cn;
        hout[m2 * 16 + lr][wid * 8 + nt * 4 + g4] = f2bf(sigm(go) * tanhf(cn));
      }
    __syncthreads();

    // store 2KB h-chunk device-coherent (rows m0..+32, cols ns*32..+32)
    {
      int row = tid >> 3, col8 = tid & 7;
      u64 v = *(const u64*)&hout[row][col8 * 4];
      u64* p = (u64*)(hbuf + (size_t)(t & 1) * (480 * 512) + (size_t)(m0 + row) * 512 + ns * 32) + col8;
      __hip_atomic_store(p, v, __ATOMIC_RELAXED, __HIP_MEMORY_SCOPE_AGENT);
    }
    asm volatile("s_waitcnt vmcnt(0)" ::: "memory");   // my stores at coherent point
    __syncthreads();                                   // all waves' stores done
    if (tid == 0)
      __hip_atomic_fetch_add(&ctr[t * 15 + mt], 1u, __ATOMIC_RELAXED, __HIP_MEMORY_SCOPE_AGENT);
  }

  // persist c for next dispatch
  #pragma unroll
  for (int m2 = 0; m2 < 2; m2++)
    #pragma unroll
    for (int nt = 0; nt < 2; nt++)
      cbuf[(size_t)(m0 + m2 * 16 + lr) * 512 + jbase + nt * 4 + g4] = c[m2][nt];
}

// ---------------- direct MFMA GEMM (MLP head) ----------------
template<int BM, int BN, int WM, int WN, int ACT, int OUTK>
__global__ __launch_bounds__(256) void mgemm_k(
    const u16* __restrict__ A, int lda,
    const u16* __restrict__ B, int ldb,
    const float* __restrict__ bias,
    void* __restrict__ Cv, int ldc, int M, int K) {
  constexpr int FM = BM / (WM * 16), FN = BN / (WN * 16);
  const int tid = threadIdx.x;
  const int wid = tid >> 6, lane = tid & 63;
  const int lr = lane & 15, lko = (lane >> 4) << 3;
  const int m0 = blockIdx.y * BM + (wid % WM) * (FM * 16);
  const int n0 = blockIdx.x * BN + (wid / WM) * (FN * 16);

  f32x4 acc[FM][FN];
  #pragma unroll
  for (int i = 0; i < FM; i++)
    #pragma unroll
    for (int j = 0; j < FN; j++) acc[i][j] = (f32x4){0.f, 0.f, 0.f, 0.f};

  const u16* Ap[FM];
  const u16* Bp[FN];
  #pragma unroll
  for (int i = 0; i < FM; i++) {
    int r = m0 + i * 16 + lr;
    if (r > M - 1) r = M - 1;
    Ap[i] = A + (size_t)r * lda + lko;
  }
  #pragma unroll
  for (int j = 0; j < FN; j++) Bp[j] = B + (size_t)(n0 + j * 16 + lr) * ldb + lko;

  #pragma unroll 2
  for (int k0 = 0; k0 < K; k0 += 32) {
    bf16x8 av[FM], bv[FN];
    #pragma unroll
    for (int i = 0; i < FM; i++) av[i] = *(const bf16x8*)(Ap[i] + k0);
    #pragma unroll
    for (int j = 0; j < FN; j++) bv[j] = *(const bf16x8*)(Bp[j] + k0);
    #pragma unroll
    for (int i = 0; i < FM; i++)
      #pragma unroll
      for (int j = 0; j < FN; j++)
        acc[i][j] = __builtin_amdgcn_mfma_f32_16x16x32_bf16(av[i], bv[j], acc[i][j], 0, 0, 0);
  }

  #pragma unroll
  for (int i = 0; i < FM; i++) {
    #pragma unroll
    for (int r = 0; r < 4; r++) {
      int m = m0 + i * 16 + ((lane >> 4) << 2) + r;
      if (m >= M) continue;
      #pragma unroll
      for (int j = 0; j < FN; j++) {
        int n = n0 + j * 16 + lr;
        float v = acc[i][j][r];
        if (bias) v += bias[n];
        if constexpr (ACT == 1) v = fmaxf(v, 0.f);
        if constexpr (ACT == 2) v = sigm(v);
        if constexpr (OUTK == 0) {
          ((float*)Cv)[(size_t)m * ldc + n] = v;
        } else if constexpr (OUTK == 1) {
          ((u16*)Cv)[(size_t)m * ldc + n] = f2bf(v);
        } else {
          if (n < 24) {
            int bb = m / 120, ll = m - bb * 120;
            ((float*)Cv)[(size_t)(bb * 24 + n) * 120 + ll] = v;
          }
        }
      }
    }
  }
}

// ---------------- launch ----------------
extern "C" void kernel_launch(void* const* d_in, const int* in_sizes, int n_in,
                              void* d_out, int out_size, void* d_ws, size_t ws_size,
                              hipStream_t stream) {
  const float* x   = (const float*)d_in[0];
  const float* Ah  = (const float*)d_in[1];
  const float* W1  = (const float*)d_in[2];
  const float* W2  = (const float*)d_in[3];
  const float* Wih = (const float*)d_in[4];
  const float* Whh = (const float*)d_in[5];
  const float* bih = (const float*)d_in[6];
  const float* bhh = (const float*)d_in[7];
  const float* Wh1 = (const float*)d_in[8];
  const float* bh1 = (const float*)d_in[9];
  const float* Wh2 = (const float*)d_in[10];
  const float* bh2 = (const float*)d_in[11];
  const float* Wh3 = (const float*)d_in[12];
  const float* bh3 = (const float*)d_in[13];
  const float* Wh4 = (const float*)d_in[14];
  const float* bh4 = (const float*)d_in[15];
  (void)in_sizes; (void)n_in; (void)out_size;

  char* ws = (char*)d_ws;
  size_t off = 0;
  auto alloc = [&](size_t bytes) -> char* {
    char* p = ws + off;
    off += (bytes + 1023) & ~(size_t)1023;
    return p;
  };

  u16 *gates, *h2c, *Wihp, *Whhp, *Wh1p, *Wh2p, *Wh3p, *Wh4p, *hbuf, *z1, *z2, *z3;
  float *pbuf, *qbuf, *c1, *c2, *biasg, *bh1p, *bh2p, *bh3p, *bh4p, *cbuf;
  unsigned* ctr;

  auto doplan = [&](int res) {
    off = 0;
    gates = (u16*)alloc((size_t)res * 480 * 2048 * 2);
    h2c   = (u16*)alloc((size_t)res * 480 * 512 * 2);
    pbuf  = (float*)alloc((size_t)192 * 480 * 4);
    qbuf  = (float*)alloc((size_t)192 * 480 * 4);
    c1    = (float*)alloc(512 * 4);
    c2    = (float*)alloc(512 * 4);
    Wihp  = (u16*)alloc((size_t)2048 * 512 * 2);
    Whhp  = (u16*)alloc((size_t)2048 * 512 * 2);
    Wh1p  = (u16*)alloc((size_t)3072 * 512 * 2);
    Wh2p  = (u16*)alloc((size_t)1024 * 3072 * 2);
    Wh3p  = (u16*)alloc((size_t)3072 * 1024 * 2);
    Wh4p  = (u16*)alloc((size_t)128 * 3072 * 2);
    biasg = (float*)alloc(2048 * 4);
    bh1p  = (float*)alloc(3072 * 4);
    bh2p  = (float*)alloc(1024 * 4);
    bh3p  = (float*)alloc(3072 * 4);
    bh4p  = (float*)alloc(128 * 4);
    // hbuf(2 parity) + cbuf + ctr contiguous -> zeroed in one kernel
    hbuf  = (u16*)alloc((size_t)2 * 480 * 512 * 2);
    cbuf  = (float*)alloc((size_t)480 * 512 * 4);
    ctr   = (unsigned*)alloc(12288);          // 192*15 counters
    z1    = (u16*)alloc((size_t)480 * 3072 * 2);
    z2    = (u16*)alloc((size_t)480 * 1024 * 2);
    z3    = (u16*)alloc((size_t)480 * 3072 * 2);
  };
  int RES = 192; doplan(RES);
  if (off > ws_size) { RES = 96; doplan(RES); }
  if (off > ws_size) { RES = 48; doplan(RES); }
  if (off > ws_size) { RES = 16; doplan(RES); }

  // ---- weight packing ----
  packgate_k<<<4096, 256, 0, stream>>>(Wih, Wihp);
  packgate_k<<<4096, 256, 0, stream>>>(Whh, Whhp);
  gatebias_k<<<8, 256, 0, stream>>>(bih, bhh, biasg);
  packT_k<<<6144, 256, 0, stream>>>(Wh1, 500, 3000, Wh1p, 3072, 512);
  packT_k<<<12288, 256, 0, stream>>>(Wh2, 3000, 1000, Wh2p, 1024, 3072);
  packT_k<<<12288, 256, 0, stream>>>(Wh3, 1000, 3000, Wh3p, 3072, 1024);
  packT_k<<<1536, 256, 0, stream>>>(Wh4, 3000, 24, Wh4p, 128, 3072);
  padbias_k<<<12, 256, 0, stream>>>(bh1, 3000, bh1p, 3072);
  padbias_k<<<4, 256, 0, stream>>>(bh2, 1000, bh2p, 1024);
  padbias_k<<<12, 256, 0, stream>>>(bh3, 3000, bh3p, 3072);
  padbias_k<<<1, 256, 0, stream>>>(bh4, 24, bh4p, 128);

  // ---- GCN rank-2 front ----
  c12_k<<<2, 256, 0, stream>>>(W1, W2, c1, c2);
  pq_k<<<768, 128, 0, stream>>>(x, Ah, pbuf, qbuf);

  // zero hbuf(2x) + cbuf + ctr: contiguous 983040 + 983040 + 12288 = 1978368 B
  zero_k<<<1932, 256, 0, stream>>>((uint32_t*)hbuf, 494592);

  const int NCH = 192 / RES;
  for (int ci = 0; ci < NCH; ci++) {
    int t0 = ci * RES;
    int M = RES * 480;
    h2mat_k<<<M / 4, 256, 0, stream>>>(pbuf, qbuf, c1, c2, h2c, t0 * 480);
    gemm_lds_k<<<dim3(16, M / 128), 256, 0, stream>>>(h2c, Wihp, biasg, gates, M);
    lstm_flag_k<<<240, 256, 0, stream>>>(Whhp, gates, hbuf, cbuf, ctr, t0, t0 + RES);
  }

  // ---- MLP head: h_last = hbuf parity 1 (t=191 odd) ----
  const u16* hlast = hbuf + 480 * 512;
  mgemm_k<32, 256, 1, 4, 1, 1><<<dim3(12, 15), 256, 0, stream>>>(
      hlast, 512, Wh1p, 512, bh1p, z1, 3072, 480, 512);
  mgemm_k<32, 256, 1, 4, 1, 1><<<dim3(4, 15), 256, 0, stream>>>(
      z1, 3072, Wh2p, 3072, bh2p, z2, 1024, 480, 3072);
  mgemm_k<32, 256, 1, 4, 1, 1><<<dim3(12, 15), 256, 0, stream>>>(
      z2, 1024, Wh3p, 1024, bh3p, z3, 3072, 480, 1024);
  mgemm_k<32, 128, 1, 4, 2, 2><<<dim3(1, 15), 256, 0, stream>>>(
      z3, 3072, Wh4p, 3072, bh4p, d_out, 0, 480, 3072);
}

// Round 7
// 1833.050 us; speedup vs baseline: 16.4426x; 1.2881x over previous
//
#include <hip/hip_runtime.h>
#include <stdint.h>

typedef unsigned short u16;
typedef unsigned long long u64;
typedef short bf16x8 __attribute__((ext_vector_type(8)));
typedef float f32x4 __attribute__((ext_vector_type(4)));

__device__ __forceinline__ float bf2f(u16 u) {
  union { uint32_t i; float f; } v; v.i = ((uint32_t)u) << 16; return v.f;
}
__device__ __forceinline__ u16 f2bf(float f) {
  union { float f; uint32_t i; } v; v.f = f;
  uint32_t x = v.i;
  return (u16)((x + 0x7FFFu + ((x >> 16) & 1u)) >> 16);
}
__device__ __forceinline__ float sigm(float x) { return 1.f / (1.f + expf(-x)); }

// ---------------- packing ----------------
// Wih/Whh [2000][500] f32 -> [2048][512] bf16, rows interleaved c = j*4+g
__global__ void packgate_k(const float* __restrict__ src, u16* __restrict__ dst) {
  int idx = blockIdx.x * 256 + threadIdx.x;
  if (idx >= 2048 * 512) return;
  int crow = idx >> 9, k = idx & 511;
  int j = crow >> 2, g = crow & 3;
  u16 v = 0;
  if (j < 500 && k < 500) v = f2bf(src[(size_t)(g * 500 + j) * 500 + k]);
  dst[idx] = v;
}

__global__ void gatebias_k(const float* __restrict__ bih, const float* __restrict__ bhh,
                           float* __restrict__ dst) {
  int c = blockIdx.x * 256 + threadIdx.x;
  if (c >= 2048) return;
  int j = c >> 2, g = c & 3;
  dst[c] = (j < 500) ? bih[g * 500 + j] + bhh[g * 500 + j] : 0.f;
}

// src f32 [Ks][Ns] -> dst bf16 [Nd][Kd] (transposed, zero-padded)
__global__ void packT_k(const float* __restrict__ src, int Ks, int Ns,
                        u16* __restrict__ dst, int Nd, int Kd) {
  int idx = blockIdx.x * 256 + threadIdx.x;
  if (idx >= Nd * Kd) return;
  int n = idx / Kd, k = idx - n * Kd;
  dst[idx] = (n < Ns && k < Ks) ? f2bf(src[(size_t)k * Ns + n]) : (u16)0;
}

__global__ void padbias_k(const float* __restrict__ s, int Ns, float* __restrict__ dst, int Nd) {
  int i = blockIdx.x * 256 + threadIdx.x;
  if (i >= Nd) return;
  dst[i] = (i < Ns) ? s[i] : 0.f;
}

__global__ void zero_k(uint32_t* __restrict__ p, int n) {
  int i = blockIdx.x * 256 + threadIdx.x;
  if (i < n) p[i] = 0u;
}

// ---------------- c1 = W2^T W1+, c2 = W2^T W1- ----------------
__global__ void c12_k(const float* __restrict__ W1, const float* __restrict__ W2,
                      float* __restrict__ c1, float* __restrict__ c2) {
  int f = blockIdx.x * 256 + threadIdx.x;
  if (f >= 512) return;
  float s1 = 0.f, s2 = 0.f;
  if (f < 500) {
    for (int g = 0; g < 500; g++) {
      float w = W1[g];
      float v = W2[(size_t)g * 500 + f];
      s1 = fmaf(fmaxf(w, 0.f), v, s1);
      s2 = fmaf(fminf(w, 0.f), v, s2);
    }
  }
  c1[f] = s1; c2[f] = s2;
}

// ---------------- p = A@(A@x)+, q = A@(A@x)- ----------------
__global__ void pq_k(const float* __restrict__ x, const float* __restrict__ A,
                     float* __restrict__ p, float* __restrict__ q) {
  __shared__ float xs[120], axp[120], axm[120];
  int bt = blockIdx.x, tid = threadIdx.x;
  int t = bt >> 2, b = bt & 3;
  if (tid < 120) xs[tid] = x[(size_t)(b * 192 + t) * 120 + tid];
  __syncthreads();
  if (tid < 120) {
    const float* Ar = A + tid * 120;
    float s = 0.f;
    for (int j = 0; j < 120; j++) s = fmaf(Ar[j], xs[j], s);
    axp[tid] = fmaxf(s, 0.f);
    axm[tid] = fminf(s, 0.f);
  }
  __syncthreads();
  if (tid < 120) {
    const float* Ar = A + tid * 120;
    float sp = 0.f, sm = 0.f;
    for (int j = 0; j < 120; j++) { float a = Ar[j]; sp = fmaf(a, axp[j], sp); sm = fmaf(a, axm[j], sm); }
    int o = t * 480 + b * 120 + tid;
    p[o] = sp; q[o] = sm;
  }
}

// ---------------- h2 = relu(p*c1 + q*c2), bf16 rows ----------------
__global__ void h2mat_k(const float* __restrict__ p, const float* __restrict__ q,
                        const float* __restrict__ c1, const float* __restrict__ c2,
                        u16* __restrict__ h2c, int R0) {
  int row = blockIdx.x * 4 + (threadIdx.x >> 6);
  int go = (threadIdx.x & 63) * 8;
  float pv = p[R0 + row], qv = q[R0 + row];
  alignas(16) u16 o[8];
  #pragma unroll
  for (int i = 0; i < 8; i++) {
    float v = pv * c1[go + i] + qv * c2[go + i];
    o[i] = f2bf(fmaxf(v, 0.f));
  }
  *(uint4*)&h2c[(size_t)row * 512 + go] = *(const uint4*)o;
}

// ---------------- LDS-staged gates GEMM: C = A @ B^T + bias (bf16 out) ----------------
__global__ __launch_bounds__(256, 2) void gemm_lds_k(
    const u16* __restrict__ A, const u16* __restrict__ B,
    const float* __restrict__ bias, u16* __restrict__ C, int M) {
  __shared__ u16 Al[2][128][32];
  __shared__ u16 Bl[2][128][32];
  const int tid = threadIdx.x, wid = tid >> 6, lane = tid & 63;
  const int lr = lane & 15, g4 = lane >> 4;
  const int m0 = blockIdx.y * 128, n0 = blockIdx.x * 128;
  const int ms = (wid & 1) * 64, ns = (wid >> 1) * 64;
  const int srow = tid >> 1, shalf = (tid & 1) * 16;
  const u16* Asrc = A + (size_t)(m0 + srow) * 512 + shalf;
  const u16* Bsrc = B + (size_t)(n0 + srow) * 512 + shalf;

  f32x4 acc[4][4];
  #pragma unroll
  for (int i = 0; i < 4; i++)
    #pragma unroll
    for (int j = 0; j < 4; j++) acc[i][j] = (f32x4){0.f, 0.f, 0.f, 0.f};

  uint4 ra0, ra1, rb0, rb1;
  ra0 = *(const uint4*)(Asrc + 0);  ra1 = *(const uint4*)(Asrc + 8);
  rb0 = *(const uint4*)(Bsrc + 0);  rb1 = *(const uint4*)(Bsrc + 8);
  *(uint4*)&Al[0][srow][shalf] = ra0; *(uint4*)&Al[0][srow][shalf + 8] = ra1;
  *(uint4*)&Bl[0][srow][shalf] = rb0; *(uint4*)&Bl[0][srow][shalf + 8] = rb1;
  ra0 = *(const uint4*)(Asrc + 32); ra1 = *(const uint4*)(Asrc + 40);
  rb0 = *(const uint4*)(Bsrc + 32); rb1 = *(const uint4*)(Bsrc + 40);
  __syncthreads();

  #pragma unroll
  for (int kt = 0; kt < 16; kt++) {
    const int cur = kt & 1;
    if (kt < 15) {
      *(uint4*)&Al[cur ^ 1][srow][shalf] = ra0; *(uint4*)&Al[cur ^ 1][srow][shalf + 8] = ra1;
      *(uint4*)&Bl[cur ^ 1][srow][shalf] = rb0; *(uint4*)&Bl[cur ^ 1][srow][shalf + 8] = rb1;
    }
    if (kt < 14) {
      ra0 = *(const uint4*)(Asrc + (kt + 2) * 32);     ra1 = *(const uint4*)(Asrc + (kt + 2) * 32 + 8);
      rb0 = *(const uint4*)(Bsrc + (kt + 2) * 32);     rb1 = *(const uint4*)(Bsrc + (kt + 2) * 32 + 8);
    }
    bf16x8 av[4], bv[4];
    #pragma unroll
    for (int i = 0; i < 4; i++) av[i] = *(const bf16x8*)&Al[cur][ms + i * 16 + lr][g4 * 8];
    #pragma unroll
    for (int j = 0; j < 4; j++) bv[j] = *(const bf16x8*)&Bl[cur][ns + j * 16 + lr][g4 * 8];
    #pragma unroll
    for (int i = 0; i < 4; i++)
      #pragma unroll
      for (int j = 0; j < 4; j++)
        acc[i][j] = __builtin_amdgcn_mfma_f32_16x16x32_bf16(av[i], bv[j], acc[i][j], 0, 0, 0);
    __syncthreads();
  }

  #pragma unroll
  for (int i = 0; i < 4; i++)
    #pragma unroll
    for (int r = 0; r < 4; r++) {
      int m = m0 + ms + i * 16 + g4 * 4 + r;
      #pragma unroll
      for (int j = 0; j < 4; j++) {
        int n = n0 + ns + j * 16 + lr;
        C[(size_t)m * 2048 + n] = f2bf(acc[i][j][r] + bias[n]);
      }
    }
}

// ---------------- flag-synced persistent LSTM, Whh register-stationary ----------------
// Grid 256 = 16 m-tile groups x 16 n-slices; group 15 exits (480 rows = 15 x 32).
// mt = (bid&7)*2 + ((bid>>3)&1): with bid%8 XCD round-robin, all 16 siblings of a
// group land on ONE XCD (perf heuristic only; correctness via agent-scope atomics).
// h exchanged via relaxed agent u64 stores/loads; per-(t,mt) counters, target 64
// (16 blocks x 4 waves, per-wave arrival after own vmcnt). Gates prefetched 1 step.
__global__ __launch_bounds__(256, 1) void lstm_flag_k(
    const u16* __restrict__ Whh, const u16* __restrict__ gates,
    u16* __restrict__ hbuf, float* __restrict__ cbuf,
    unsigned* __restrict__ ctr, int t0, int t1) {
  __shared__ u16 hls[32][520];
  __shared__ u16 hout[32][36];
  const int tid = threadIdx.x, wid = tid >> 6, lane = tid & 63;
  const int lr = lane & 15, g4 = lane >> 4;
  const int bid = blockIdx.x;
  const int mt = ((bid & 7) << 1) | ((bid >> 3) & 1);
  const int ns = bid >> 4;
  if (mt >= 15) return;
  const int m0 = mt * 32;
  const int colbase = ns * 128 + wid * 32;
  const int jbase = ns * 32 + wid * 8;

  // Whh slice -> registers (stationary across all steps)
  bf16x8 bv[2][16];
  #pragma unroll
  for (int nt = 0; nt < 2; nt++)
    #pragma unroll
    for (int kk = 0; kk < 16; kk++)
      bv[nt][kk] = *(const bf16x8*)(Whh + (size_t)(colbase + nt * 16 + lr) * 512 + kk * 32 + g4 * 8);

  float c[2][2];
  #pragma unroll
  for (int m2 = 0; m2 < 2; m2++)
    #pragma unroll
    for (int nt = 0; nt < 2; nt++)
      c[m2][nt] = cbuf[(size_t)(m0 + m2 * 16 + lr) * 512 + jbase + nt * 4 + g4];

  // prologue: gates quads for t0
  uint2 gqc[2][2], gqn[2][2];
  #pragma unroll
  for (int m2 = 0; m2 < 2; m2++)
    #pragma unroll
    for (int nt = 0; nt < 2; nt++)
      gqc[m2][nt] = *(const uint2*)(gates + (size_t)(m0 + m2 * 16 + lr) * 2048 + colbase + nt * 16 + g4 * 4);

  for (int t = t0; t < t1; ++t) {
    // wait for my group's h_{t-1} producers (skip at dispatch boundary)
    if (t > t0) {
      if (tid == 0) {
        while (__hip_atomic_load(&ctr[(t - 1) * 15 + mt], __ATOMIC_RELAXED,
                                 __HIP_MEMORY_SCOPE_AGENT) < 64u)
          __builtin_amdgcn_s_sleep(1);
      }
      __syncthreads();
    }
    // fill LDS h-tile (32 rows x 512 cols) via device-coherent u64 loads
    const u16* hsrc = hbuf + ((t + 1) & 1) * (480 * 512);
    u64 vf[16];
    #pragma unroll
    for (int k = 0; k < 16; k++) {
      int i = k * 256 + tid;
      int row = i >> 7, col8 = i & 127;
      const u64* p = (const u64*)(hsrc + (size_t)(m0 + row) * 512) + col8;
      vf[k] = __hip_atomic_load(p, __ATOMIC_RELAXED, __HIP_MEMORY_SCOPE_AGENT);
    }
    // prefetch next step's gates while h loads are in flight
    {
      int tn = (t + 1 < t1) ? (t + 1) : t;
      const u16* gsrc = gates + (size_t)(tn - t0) * 480 * 2048;
      #pragma unroll
      for (int m2 = 0; m2 < 2; m2++)
        #pragma unroll
        for (int nt = 0; nt < 2; nt++)
          gqn[m2][nt] = *(const uint2*)(gsrc + (size_t)(m0 + m2 * 16 + lr) * 2048 + colbase + nt * 16 + g4 * 4);
    }
    #pragma unroll
    for (int k = 0; k < 16; k++) {
      int i = k * 256 + tid;
      int row = i >> 7, col8 = i & 127;
      *(u64*)&hls[row][col8 * 4] = vf[k];
    }
    __syncthreads();

    f32x4 acc[2][2];
    #pragma unroll
    for (int m2 = 0; m2 < 2; m2++)
      #pragma unroll
      for (int nt = 0; nt < 2; nt++) acc[m2][nt] = (f32x4){0.f, 0.f, 0.f, 0.f};
    #pragma unroll
    for (int kk = 0; kk < 16; kk++) {
      bf16x8 av0 = *(const bf16x8*)&hls[lr][kk * 32 + g4 * 8];
      bf16x8 av1 = *(const bf16x8*)&hls[16 + lr][kk * 32 + g4 * 8];
      acc[0][0] = __builtin_amdgcn_mfma_f32_16x16x32_bf16(bv[0][kk], av0, acc[0][0], 0, 0, 0);
      acc[0][1] = __builtin_amdgcn_mfma_f32_16x16x32_bf16(bv[1][kk], av0, acc[0][1], 0, 0, 0);
      acc[1][0] = __builtin_amdgcn_mfma_f32_16x16x32_bf16(bv[0][kk], av1, acc[1][0], 0, 0, 0);
      acc[1][1] = __builtin_amdgcn_mfma_f32_16x16x32_bf16(bv[1][kk], av1, acc[1][1], 0, 0, 0);
    }

    // cell (lane-local quads) -> LDS pack
    #pragma unroll
    for (int m2 = 0; m2 < 2; m2++)
      #pragma unroll
      for (int nt = 0; nt < 2; nt++) {
        const u16* gp = (const u16*)&gqc[m2][nt];
        float gi = bf2f(gp[0]) + acc[m2][nt][0];
        float gf = bf2f(gp[1]) + acc[m2][nt][1];
        float gg = bf2f(gp[2]) + acc[m2][nt][2];
        float go = bf2f(gp[3]) + acc[m2][nt][3];
        float cn = sigm(gf) * c[m2][nt] + sigm(gi) * tanhf(gg);
        c[m2][nt] = cn;
        hout[m2 * 16 + lr][wid * 8 + nt * 4 + g4] = f2bf(sigm(go) * tanhf(cn));
      }
    __syncthreads();

    // store 2KB h-chunk device-coherent (rows m0..+32, cols ns*32..+32)
    {
      int row = tid >> 3, col8 = tid & 7;
      u64 v = *(const u64*)&hout[row][col8 * 4];
      u64* p = (u64*)(hbuf + (size_t)(t & 1) * (480 * 512) + (size_t)(m0 + row) * 512 + ns * 32) + col8;
      __hip_atomic_store(p, v, __ATOMIC_RELAXED, __HIP_MEMORY_SCOPE_AGENT);
    }
    asm volatile("s_waitcnt vmcnt(0)" ::: "memory");   // this wave's stores at coherent point
    if (lane == 0)
      __hip_atomic_fetch_add(&ctr[t * 15 + mt], 1u, __ATOMIC_RELAXED, __HIP_MEMORY_SCOPE_AGENT);
    #pragma unroll
    for (int m2 = 0; m2 < 2; m2++)
      #pragma unroll
      for (int nt = 0; nt < 2; nt++) gqc[m2][nt] = gqn[m2][nt];
  }

  // persist c for next dispatch
  #pragma unroll
  for (int m2 = 0; m2 < 2; m2++)
    #pragma unroll
    for (int nt = 0; nt < 2; nt++)
      cbuf[(size_t)(m0 + m2 * 16 + lr) * 512 + jbase + nt * 4 + g4] = c[m2][nt];
}

// ---------------- direct MFMA GEMM (MLP head) ----------------
template<int BM, int BN, int WM, int WN, int ACT, int OUTK>
__global__ __launch_bounds__(256) void mgemm_k(
    const u16* __restrict__ A, int lda,
    const u16* __restrict__ B, int ldb,
    const float* __restrict__ bias,
    void* __restrict__ Cv, int ldc, int M, int K) {
  constexpr int FM = BM / (WM * 16), FN = BN / (WN * 16);
  const int tid = threadIdx.x;
  const int wid = tid >> 6, lane = tid & 63;
  const int lr = lane & 15, lko = (lane >> 4) << 3;
  const int m0 = blockIdx.y * BM + (wid % WM) * (FM * 16);
  const int n0 = blockIdx.x * BN + (wid / WM) * (FN * 16);

  f32x4 acc[FM][FN];
  #pragma unroll
  for (int i = 0; i < FM; i++)
    #pragma unroll
    for (int j = 0; j < FN; j++) acc[i][j] = (f32x4){0.f, 0.f, 0.f, 0.f};

  const u16* Ap[FM];
  const u16* Bp[FN];
  #pragma unroll
  for (int i = 0; i < FM; i++) {
    int r = m0 + i * 16 + lr;
    if (r > M - 1) r = M - 1;
    Ap[i] = A + (size_t)r * lda + lko;
  }
  #pragma unroll
  for (int j = 0; j < FN; j++) Bp[j] = B + (size_t)(n0 + j * 16 + lr) * ldb + lko;

  #pragma unroll 2
  for (int k0 = 0; k0 < K; k0 += 32) {
    bf16x8 av[FM], bv[FN];
    #pragma unroll
    for (int i = 0; i < FM; i++) av[i] = *(const bf16x8*)(Ap[i] + k0);
    #pragma unroll
    for (int j = 0; j < FN; j++) bv[j] = *(const bf16x8*)(Bp[j] + k0);
    #pragma unroll
    for (int i = 0; i < FM; i++)
      #pragma unroll
      for (int j = 0; j < FN; j++)
        acc[i][j] = __builtin_amdgcn_mfma_f32_16x16x32_bf16(av[i], bv[j], acc[i][j], 0, 0, 0);
  }

  #pragma unroll
  for (int i = 0; i < FM; i++) {
    #pragma unroll
    for (int r = 0; r < 4; r++) {
      int m = m0 + i * 16 + ((lane >> 4) << 2) + r;
      if (m >= M) continue;
      #pragma unroll
      for (int j = 0; j < FN; j++) {
        int n = n0 + j * 16 + lr;
        float v = acc[i][j][r];
        if (bias) v += bias[n];
        if constexpr (ACT == 1) v = fmaxf(v, 0.f);
        if constexpr (ACT == 2) v = sigm(v);
        if constexpr (OUTK == 0) {
          ((float*)Cv)[(size_t)m * ldc + n] = v;
        } else if constexpr (OUTK == 1) {
          ((u16*)Cv)[(size_t)m * ldc + n] = f2bf(v);
        } else {
          if (n < 24) {
            int bb = m / 120, ll = m - bb * 120;
            ((float*)Cv)[(size_t)(bb * 24 + n) * 120 + ll] = v;
          }
        }
      }
    }
  }
}

// ---------------- launch ----------------
extern "C" void kernel_launch(void* const* d_in, const int* in_sizes, int n_in,
                              void* d_out, int out_size, void* d_ws, size_t ws_size,
                              hipStream_t stream) {
  const float* x   = (const float*)d_in[0];
  const float* Ah  = (const float*)d_in[1];
  const float* W1  = (const float*)d_in[2];
  const float* W2  = (const float*)d_in[3];
  const float* Wih = (const float*)d_in[4];
  const float* Whh = (const float*)d_in[5];
  const float* bih = (const float*)d_in[6];
  const float* bhh = (const float*)d_in[7];
  const float* Wh1 = (const float*)d_in[8];
  const float* bh1 = (const float*)d_in[9];
  const float* Wh2 = (const float*)d_in[10];
  const float* bh2 = (const float*)d_in[11];
  const float* Wh3 = (const float*)d_in[12];
  const float* bh3 = (const float*)d_in[13];
  const float* Wh4 = (const float*)d_in[14];
  const float* bh4 = (const float*)d_in[15];
  (void)in_sizes; (void)n_in; (void)out_size;

  char* ws = (char*)d_ws;
  size_t off = 0;
  auto alloc = [&](size_t bytes) -> char* {
    char* p = ws + off;
    off += (bytes + 1023) & ~(size_t)1023;
    return p;
  };

  u16 *gates, *h2c, *Wihp, *Whhp, *Wh1p, *Wh2p, *Wh3p, *Wh4p, *hbuf, *z1, *z2, *z3;
  float *pbuf, *qbuf, *c1, *c2, *biasg, *bh1p, *bh2p, *bh3p, *bh4p, *cbuf;
  unsigned* ctr;

  auto doplan = [&](int res) {
    off = 0;
    gates = (u16*)alloc((size_t)res * 480 * 2048 * 2);
    h2c   = (u16*)alloc((size_t)res * 480 * 512 * 2);
    pbuf  = (float*)alloc((size_t)192 * 480 * 4);
    qbuf  = (float*)alloc((size_t)192 * 480 * 4);
    c1    = (float*)alloc(512 * 4);
    c2    = (float*)alloc(512 * 4);
    Wihp  = (u16*)alloc((size_t)2048 * 512 * 2);
    Whhp  = (u16*)alloc((size_t)2048 * 512 * 2);
    Wh1p  = (u16*)alloc((size_t)3072 * 512 * 2);
    Wh2p  = (u16*)alloc((size_t)1024 * 3072 * 2);
    Wh3p  = (u16*)alloc((size_t)3072 * 1024 * 2);
    Wh4p  = (u16*)alloc((size_t)128 * 3072 * 2);
    biasg = (float*)alloc(2048 * 4);
    bh1p  = (float*)alloc(3072 * 4);
    bh2p  = (float*)alloc(1024 * 4);
    bh3p  = (float*)alloc(3072 * 4);
    bh4p  = (float*)alloc(128 * 4);
    // hbuf(2 parity) + cbuf + ctr contiguous -> zeroed in one kernel
    hbuf  = (u16*)alloc((size_t)2 * 480 * 512 * 2);
    cbuf  = (float*)alloc((size_t)480 * 512 * 4);
    ctr   = (unsigned*)alloc(12288);          // 192*15 counters
    z1    = (u16*)alloc((size_t)480 * 3072 * 2);
    z2    = (u16*)alloc((size_t)480 * 1024 * 2);
    z3    = (u16*)alloc((size_t)480 * 3072 * 2);
  };
  int RES = 192; doplan(RES);
  if (off > ws_size) { RES = 96; doplan(RES); }
  if (off > ws_size) { RES = 48; doplan(RES); }
  if (off > ws_size) { RES = 16; doplan(RES); }

  // ---- weight packing ----
  packgate_k<<<4096, 256, 0, stream>>>(Wih, Wihp);
  packgate_k<<<4096, 256, 0, stream>>>(Whh, Whhp);
  gatebias_k<<<8, 256, 0, stream>>>(bih, bhh, biasg);
  packT_k<<<6144, 256, 0, stream>>>(Wh1, 500, 3000, Wh1p, 3072, 512);
  packT_k<<<12288, 256, 0, stream>>>(Wh2, 3000, 1000, Wh2p, 1024, 3072);
  packT_k<<<12288, 256, 0, stream>>>(Wh3, 1000, 3000, Wh3p, 3072, 1024);
  packT_k<<<1536, 256, 0, stream>>>(Wh4, 3000, 24, Wh4p, 128, 3072);
  padbias_k<<<12, 256, 0, stream>>>(bh1, 3000, bh1p, 3072);
  padbias_k<<<4, 256, 0, stream>>>(bh2, 1000, bh2p, 1024);
  padbias_k<<<12, 256, 0, stream>>>(bh3, 3000, bh3p, 3072);
  padbias_k<<<1, 256, 0, stream>>>(bh4, 24, bh4p, 128);

  // ---- GCN rank-2 front ----
  c12_k<<<2, 256, 0, stream>>>(W1, W2, c1, c2);
  pq_k<<<768, 128, 0, stream>>>(x, Ah, pbuf, qbuf);

  // zero hbuf(2x) + cbuf + ctr: contiguous 983040 + 983040 + 12288 = 1978368 B
  zero_k<<<1932, 256, 0, stream>>>((uint32_t*)hbuf, 494592);

  const int NCH = 192 / RES;
  for (int ci = 0; ci < NCH; ci++) {
    int t0 = ci * RES;
    int M = RES * 480;
    h2mat_k<<<M / 4, 256, 0, stream>>>(pbuf, qbuf, c1, c2, h2c, t0 * 480);
    gemm_lds_k<<<dim3(16, M / 128), 256, 0, stream>>>(h2c, Wihp, biasg, gates, M);
    lstm_flag_k<<<256, 256, 0, stream>>>(Whhp, gates, hbuf, cbuf, ctr, t0, t0 + RES);
  }

  // ---- MLP head: h_last = hbuf parity 1 (t=191 odd) ----
  const u16* hlast = hbuf + 480 * 512;
  mgemm_k<32, 256, 1, 4, 1, 1><<<dim3(12, 15), 256, 0, stream>>>(
      hlast, 512, Wh1p, 512, bh1p, z1, 3072, 480, 512);
  mgemm_k<32, 256, 1, 4, 1, 1><<<dim3(4, 15), 256, 0, stream>>>(
      z1, 3072, Wh2p, 3072, bh2p, z2, 1024, 480, 3072);
  mgemm_k<32, 256, 1, 4, 1, 1><<<dim3(12, 15), 256, 0, stream>>>(
      z2, 1024, Wh3p, 1024, bh3p, z3, 3072, 480, 1024);
  mgemm_k<32, 128, 1, 4, 2, 2><<<dim3(1, 15), 256, 0, stream>>>(
      z3, 3072, Wh4p, 3072, bh4p, d_out, 0, 480, 3072);
}